// Round 1
// baseline (6737.785 us; speedup 1.0000x reference)
//
#include <hip/hip_runtime.h>
#include <stdint.h>

// Problem constants (from reference)
#define NN 20000     // nodes
#define NE 320000    // edges
#define HH 256       // hidden
#define EDK 64       // edge_dim
#define NSTEPS 4
#define ECH 80000    // edge chunk (Pe buffer sized for one chunk)
#define NCHUNK 4

__device__ __forceinline__ float silu_f(float x) { return x / (1.0f + __expf(-x)); }

// ---------------- LayerNorm: one wave per row of 256 floats ----------------
__global__ void ln_kernel(const float* __restrict__ x, const float* __restrict__ g,
                          const float* __restrict__ b, float* __restrict__ y, int M)
{
    int row  = blockIdx.x * 4 + (threadIdx.x >> 6);
    int lane = threadIdx.x & 63;
    if (row >= M) return;
    float4 v = *(const float4*)(x + (size_t)row * HH + lane * 4);
    float s  = v.x + v.y + v.z + v.w;
    float ss = v.x*v.x + v.y*v.y + v.z*v.z + v.w*v.w;
#pragma unroll
    for (int off = 32; off > 0; off >>= 1) {
        s  += __shfl_down(s, off);
        ss += __shfl_down(ss, off);
    }
    float mean = __shfl(s, 0) * (1.0f / HH);
    float ms   = __shfl(ss, 0) * (1.0f / HH);
    float rstd = rsqrtf(ms - mean * mean + 1e-5f);
    float4 gg = *(const float4*)(g + lane * 4);
    float4 bb = *(const float4*)(b + lane * 4);
    float4 o;
    o.x = (v.x - mean) * rstd * gg.x + bb.x;
    o.y = (v.y - mean) * rstd * gg.y + bb.y;
    o.z = (v.z - mean) * rstd * gg.z + bb.z;
    o.w = (v.w - mean) * rstd * gg.w + bb.w;
    *(float4*)(y + (size_t)row * HH + lane * 4) = o;
}

// ---------------- fp32 tiled GEMM: C[M,Nc] = A[M,K] @ B[K,Nc] (+epilogue) ----------------
// EPI: 0 = acc+bias  1 = silu(acc+bias)  2 = (acc + cnt*bias)/max(cnt,1)  3 = C += acc+bias
// CONCAT: A column k<256 from A, k>=256 from A2 (both row-major with ld 256)
#define BM 64
#define BN 64
#define BK 32
template <int EPI, bool CONCAT>
__global__ __launch_bounds__(256) void gemm_kernel(
    const float* __restrict__ A, const float* __restrict__ A2, int lda,
    const float* __restrict__ B, int ldb,
    const float* __restrict__ bias, const int* __restrict__ cnt,
    float* __restrict__ C, int M, int Nc, int K)
{
    __shared__ float As[BK][BM + 4];
    __shared__ float Bs[BK][BN];
    const int tid = threadIdx.x;
    const int tx = tid & 15, ty = tid >> 4;
    const int row0 = blockIdx.x * BM, col0 = blockIdx.y * BN;
    float acc[4][4] = {};
    for (int k0 = 0; k0 < K; k0 += BK) {
        // A tile (BM x BK), stored transposed into As[k][m]
#pragma unroll
        for (int i = 0; i < 2; i++) {
            int flat = tid + i * 256;          // 0..511 float4 slots
            int r = flat >> 3, kq = flat & 7;  // r: 0..63 rows, kq: 0..7 float4-in-row
            int grow = row0 + r, kk = k0 + kq * 4;
            float4 v = make_float4(0.f, 0.f, 0.f, 0.f);
            if (grow < M) {
                if (CONCAT) {
                    const float* base = (kk < HH) ? (A  + (size_t)grow * HH + kk)
                                                  : (A2 + (size_t)grow * HH + (kk - HH));
                    v = *(const float4*)base;
                } else {
                    v = *(const float4*)(A + (size_t)grow * lda + kk);
                }
            }
            As[kq * 4 + 0][r] = v.x;
            As[kq * 4 + 1][r] = v.y;
            As[kq * 4 + 2][r] = v.z;
            As[kq * 4 + 3][r] = v.w;
        }
        // B tile (BK x BN), natural layout
#pragma unroll
        for (int i = 0; i < 2; i++) {
            int flat = tid + i * 256;
            int r = flat >> 4, cq = flat & 15;
            float4 v = *(const float4*)(B + (size_t)(k0 + r) * ldb + col0 + cq * 4);
            *(float4*)&Bs[r][cq * 4] = v;
        }
        __syncthreads();
#pragma unroll
        for (int kk = 0; kk < BK; kk++) {
            float a[4], bfr[4];
            *(float4*)a   = *(const float4*)&As[kk][ty * 4];
            *(float4*)bfr = *(const float4*)&Bs[kk][tx * 4];
#pragma unroll
            for (int i = 0; i < 4; i++)
#pragma unroll
                for (int j = 0; j < 4; j++)
                    acc[i][j] = fmaf(a[i], bfr[j], acc[i][j]);
        }
        __syncthreads();
    }
    const int ocol = col0 + tx * 4;
    float bv[4] = {0.f, 0.f, 0.f, 0.f};
    if (bias) *(float4*)bv = *(const float4*)(bias + ocol);
#pragma unroll
    for (int i = 0; i < 4; i++) {
        int r = row0 + ty * 4 + i;
        if (r >= M) break;
        float o[4];
        if (EPI == 2) {
            float cf = (float)cnt[r];
            float dg = fmaxf(cf, 1.0f);
#pragma unroll
            for (int j = 0; j < 4; j++) o[j] = (acc[i][j] + cf * bv[j]) / dg;
        } else {
#pragma unroll
            for (int j = 0; j < 4; j++) {
                o[j] = acc[i][j] + bv[j];
                if (EPI == 1) o[j] = silu_f(o[j]);
            }
        }
        float* cp = C + (size_t)r * Nc + ocol;
        if (EPI == 3) {
            float4 p = *(const float4*)cp;
            o[0] += p.x; o[1] += p.y; o[2] += p.z; o[3] += p.w;
        }
        *(float4*)cp = make_float4(o[0], o[1], o[2], o[3]);
    }
}

// ---------------- edge elementwise + scatter: u[dst] += silu(Pa[src]+Pb[dst]+Pe[e]) ----------------
// (eb1 already folded into Pe's GEMM bias). One wave per edge, lane covers 4 cols.
__global__ void edge_kernel(const float* __restrict__ Pa, const float* __restrict__ Pb,
                            const float* __restrict__ Pe, const int* __restrict__ idx,
                            float* __restrict__ u, int e0, int ecount)
{
    int gid = blockIdx.x * 256 + threadIdx.x;
    int el  = gid >> 6;
    if (el >= ecount) return;
    int lane = threadIdx.x & 63;
    int e    = e0 + el;
    int src  = idx[e];
    int dst  = idx[NE + e];
    int j    = lane * 4;
    float4 a = *(const float4*)(Pa + (size_t)src * HH + j);
    float4 b = *(const float4*)(Pb + (size_t)dst * HH + j);
    float4 c = *(const float4*)(Pe + (size_t)el * HH + j);
    float4 t;
    t.x = silu_f(a.x + b.x + c.x);
    t.y = silu_f(a.y + b.y + c.y);
    t.z = silu_f(a.z + b.z + c.z);
    t.w = silu_f(a.w + b.w + c.w);
    float* up = u + (size_t)dst * HH + j;
    atomicAdd(up + 0, t.x);
    atomicAdd(up + 1, t.y);
    atomicAdd(up + 2, t.z);
    atomicAdd(up + 3, t.w);
}

// ---------------- edge_index normalization (int64-vs-int32 autodetect) ----------------
__global__ void detect_kernel(const uint32_t* __restrict__ w, int* flag)
{
    int i = blockIdx.x * 256 + threadIdx.x;
    bool bad = false;
    if (i < NE) {  // only scan first half -> reads stay in-bounds for either layout
        uint32_t lo = w[2 * i], hi = w[2 * i + 1];
        bad = (hi != 0u) || (lo >= (uint32_t)NN);
    }
    if (__any(bad)) {
        if ((threadIdx.x & 63) == 0) atomicAnd(flag, 0);
    }
}
__global__ void convert_kernel(const uint32_t* __restrict__ w, const int* __restrict__ flag,
                               int* __restrict__ out)
{
    int i = blockIdx.x * 256 + threadIdx.x;
    if (i >= 2 * NE) return;
    out[i] = (*flag) ? (int)w[2 * i] : (int)w[i];
}
__global__ void deg_kernel(const int* __restrict__ idx, int* __restrict__ cnt)
{
    int e = blockIdx.x * 256 + threadIdx.x;
    if (e < NE) atomicAdd(cnt + idx[NE + e], 1);
}

// ---------------- launcher ----------------
extern "C" void kernel_launch(void* const* d_in, const int* in_sizes, int n_in,
                              void* d_out, int out_size, void* d_ws, size_t ws_size,
                              hipStream_t stream)
{
    const float* node_state = (const float*)d_in[0];
    const float* edge_attr  = (const float*)d_in[1];
    const float* nn_g = (const float*)d_in[2];
    const float* nn_b = (const float*)d_in[3];
    const float* mn_g = (const float*)d_in[4];
    const float* mn_b = (const float*)d_in[5];
    const float* eW1  = (const float*)d_in[6];
    const float* eb1  = (const float*)d_in[7];
    const float* eW2  = (const float*)d_in[8];
    const float* eb2  = (const float*)d_in[9];
    const float* nW1  = (const float*)d_in[10];
    const float* nb1  = (const float*)d_in[11];
    const float* nW2  = (const float*)d_in[12];
    const float* nb2  = (const float*)d_in[13];
    const uint32_t* eidx_raw = (const uint32_t*)d_in[14];

    const size_t SZ = (size_t)NN * HH;  // 5,120,000 floats
    float* ws  = (float*)d_ws;
    float* hn  = ws;
    float* Pa  = ws + SZ;
    float* Pb  = ws + 2 * SZ;
    float* u   = ws + 3 * SZ;
    float* agg = ws + 4 * SZ;
    float* big = ws + 5 * SZ;              // Pe chunk (ECH*HH) and later z (NN*512) alias here
    float* Pe  = big;
    float* z   = big;
    int* idx32 = (int*)(big + (size_t)ECH * HH);
    int* cnt   = idx32 + 2 * NE;
    int* flag  = cnt + NN;
    size_t needed = ((size_t)(flag + 1) - (size_t)d_ws);
    if (ws_size < needed) return;  // insufficient scratch: fail verification, don't crash

    float* h = (float*)d_out;

    // h <- node_state
    hipMemcpyAsync(h, node_state, SZ * sizeof(float), hipMemcpyDeviceToDevice, stream);
    // edge_index normalize + degree
    hipMemsetAsync(flag, 0xFF, sizeof(int), stream);
    detect_kernel<<<(NE + 255) / 256, 256, 0, stream>>>(eidx_raw, flag);
    convert_kernel<<<(2 * NE + 255) / 256, 256, 0, stream>>>(eidx_raw, flag, idx32);
    hipMemsetAsync(cnt, 0, NN * sizeof(int), stream);
    deg_kernel<<<(NE + 255) / 256, 256, 0, stream>>>(idx32, cnt);

    const dim3 gN4(313, 4), gN8(313, 8), gPe(ECH / BM, 4);

    for (int s = 0; s < NSTEPS; s++) {
        const float* eW1s = eW1 + (size_t)s * (2 * HH + EDK) * HH;
        const float* Wa = eW1s;
        const float* Wb = eW1s + (size_t)HH * HH;
        const float* Wc = eW1s + (size_t)2 * HH * HH;
        const float* eb1s = eb1 + (size_t)s * HH;
        const float* eW2s = eW2 + (size_t)s * HH * HH;
        const float* eb2s = eb2 + (size_t)s * HH;
        const float* nW1s = nW1 + (size_t)s * 512 * 512;
        const float* nb1s = nb1 + (size_t)s * 512;
        const float* nW2s = nW2 + (size_t)s * 512 * HH;
        const float* nb2s = nb2 + (size_t)s * HH;

        // hn = LN(h)
        ln_kernel<<<NN / 4, 256, 0, stream>>>(h, nn_g + s * HH, nn_b + s * HH, hn, NN);
        // Pa = hn @ Wa ; Pb = hn @ Wb
        gemm_kernel<0, false><<<gN4, 256, 0, stream>>>(hn, nullptr, HH, Wa, HH, nullptr, nullptr, Pa, NN, HH, HH);
        gemm_kernel<0, false><<<gN4, 256, 0, stream>>>(hn, nullptr, HH, Wb, HH, nullptr, nullptr, Pb, NN, HH, HH);
        // u = segment_sum(silu(Pa[src]+Pb[dst]+edge_attr@Wc+eb1))
        hipMemsetAsync(u, 0, SZ * sizeof(float), stream);
        for (int c = 0; c < NCHUNK; c++) {
            const float* Ach = edge_attr + (size_t)c * ECH * EDK;
            gemm_kernel<0, false><<<gPe, 256, 0, stream>>>(Ach, nullptr, EDK, Wc, HH, eb1s, nullptr, Pe, ECH, HH, EDK);
            edge_kernel<<<(ECH * 64) / 256, 256, 0, stream>>>(Pa, Pb, Pe, idx32, u, c * ECH, ECH);
        }
        // agg = LN((u @ eW2 + cnt*eb2)/max(cnt,1))
        gemm_kernel<2, false><<<gN4, 256, 0, stream>>>(u, nullptr, HH, eW2s, HH, eb2s, cnt, agg, NN, HH, HH);
        ln_kernel<<<NN / 4, 256, 0, stream>>>(agg, mn_g + s * HH, mn_b + s * HH, agg, NN);
        // z = silu([hn, agg] @ nW1 + nb1)
        gemm_kernel<1, true><<<gN8, 256, 0, stream>>>(hn, agg, HH, nW1s, 512, nb1s, nullptr, z, NN, 512, 512);
        // h += z @ nW2 + nb2
        gemm_kernel<3, false><<<gN4, 256, 0, stream>>>(z, nullptr, 512, nW2s, HH, nb2s, nullptr, h, NN, HH, 512);
    }
}

// Round 2
// 2970.477 us; speedup vs baseline: 2.2683x; 2.2683x over previous
//
#include <hip/hip_runtime.h>
#include <stdint.h>

// Problem constants (from reference)
#define NN 20000     // nodes
#define NE 320000    // edges
#define HH 256       // hidden
#define EDK 64       // edge_dim
#define NSTEPS 4
#define ECH 80000    // edge chunk (Pe buffer sized for one chunk)
#define NCHUNK 4

__device__ __forceinline__ float silu_f(float x) { return x / (1.0f + __expf(-x)); }

// ---------------- LayerNorm: one wave per row of 256 floats ----------------
__global__ void ln_kernel(const float* __restrict__ x, const float* __restrict__ g,
                          const float* __restrict__ b, float* __restrict__ y, int M)
{
    int row  = blockIdx.x * 4 + (threadIdx.x >> 6);
    int lane = threadIdx.x & 63;
    if (row >= M) return;
    float4 v = *(const float4*)(x + (size_t)row * HH + lane * 4);
    float s  = v.x + v.y + v.z + v.w;
    float ss = v.x*v.x + v.y*v.y + v.z*v.z + v.w*v.w;
#pragma unroll
    for (int off = 32; off > 0; off >>= 1) {
        s  += __shfl_down(s, off);
        ss += __shfl_down(ss, off);
    }
    float mean = __shfl(s, 0) * (1.0f / HH);
    float ms   = __shfl(ss, 0) * (1.0f / HH);
    float rstd = rsqrtf(ms - mean * mean + 1e-5f);
    float4 gg = *(const float4*)(g + lane * 4);
    float4 bb = *(const float4*)(b + lane * 4);
    float4 o;
    o.x = (v.x - mean) * rstd * gg.x + bb.x;
    o.y = (v.y - mean) * rstd * gg.y + bb.y;
    o.z = (v.z - mean) * rstd * gg.z + bb.z;
    o.w = (v.w - mean) * rstd * gg.w + bb.w;
    *(float4*)(y + (size_t)row * HH + lane * 4) = o;
}

// ---------------- fp32 tiled GEMM: C[M,Nc] = A[M,K] @ B[K,Nc] (+epilogue) ----------------
// EPI: 0 = acc+bias  1 = silu(acc+bias)  2 = (acc + cnt*bias)/max(cnt,1)  3 = C += acc+bias
// CONCAT: A column k<256 from A, k>=256 from A2 (both row-major with ld 256)
// GATHER: A row r is Aidx[rowoff + r] (row-major, ld = lda)
#define BM 64
#define BN 64
#define BK 32
template <int EPI, bool CONCAT, bool GATHER>
__global__ __launch_bounds__(256) void gemm_kernel(
    const float* __restrict__ A, const float* __restrict__ A2, int lda,
    const float* __restrict__ B, int ldb,
    const float* __restrict__ bias, const int* __restrict__ cnt,
    const int* __restrict__ Aidx, int rowoff,
    float* __restrict__ C, int M, int Nc, int K)
{
    __shared__ float As[BK][BM + 4];
    __shared__ float Bs[BK][BN];
    const int tid = threadIdx.x;
    const int tx = tid & 15, ty = tid >> 4;
    const int row0 = blockIdx.x * BM, col0 = blockIdx.y * BN;
    float acc[4][4] = {};
    for (int k0 = 0; k0 < K; k0 += BK) {
        // A tile (BM x BK), stored transposed into As[k][m]
#pragma unroll
        for (int i = 0; i < 2; i++) {
            int flat = tid + i * 256;          // 0..511 float4 slots
            int r = flat >> 3, kq = flat & 7;  // r: 0..63 rows, kq: 0..7 float4-in-row
            int grow = row0 + r, kk = k0 + kq * 4;
            float4 v = make_float4(0.f, 0.f, 0.f, 0.f);
            if (grow < M) {
                if (CONCAT) {
                    const float* base = (kk < HH) ? (A  + (size_t)grow * HH + kk)
                                                  : (A2 + (size_t)grow * HH + (kk - HH));
                    v = *(const float4*)base;
                } else if (GATHER) {
                    int arow = Aidx[rowoff + grow];
                    v = *(const float4*)(A + (size_t)arow * lda + kk);
                } else {
                    v = *(const float4*)(A + (size_t)grow * lda + kk);
                }
            }
            As[kq * 4 + 0][r] = v.x;
            As[kq * 4 + 1][r] = v.y;
            As[kq * 4 + 2][r] = v.z;
            As[kq * 4 + 3][r] = v.w;
        }
        // B tile (BK x BN), natural layout
#pragma unroll
        for (int i = 0; i < 2; i++) {
            int flat = tid + i * 256;
            int r = flat >> 4, cq = flat & 15;
            float4 v = *(const float4*)(B + (size_t)(k0 + r) * ldb + col0 + cq * 4);
            *(float4*)&Bs[r][cq * 4] = v;
        }
        __syncthreads();
#pragma unroll
        for (int kk = 0; kk < BK; kk++) {
            float a[4], bfr[4];
            *(float4*)a   = *(const float4*)&As[kk][ty * 4];
            *(float4*)bfr = *(const float4*)&Bs[kk][tx * 4];
#pragma unroll
            for (int i = 0; i < 4; i++)
#pragma unroll
                for (int j = 0; j < 4; j++)
                    acc[i][j] = fmaf(a[i], bfr[j], acc[i][j]);
        }
        __syncthreads();
    }
    const int ocol = col0 + tx * 4;
    float bv[4] = {0.f, 0.f, 0.f, 0.f};
    if (bias) *(float4*)bv = *(const float4*)(bias + ocol);
#pragma unroll
    for (int i = 0; i < 4; i++) {
        int r = row0 + ty * 4 + i;
        if (r >= M) break;
        float o[4];
        if (EPI == 2) {
            float cf = (float)cnt[r];
            float dg = fmaxf(cf, 1.0f);
#pragma unroll
            for (int j = 0; j < 4; j++) o[j] = (acc[i][j] + cf * bv[j]) / dg;
        } else {
#pragma unroll
            for (int j = 0; j < 4; j++) {
                o[j] = acc[i][j] + bv[j];
                if (EPI == 1) o[j] = silu_f(o[j]);
            }
        }
        float* cp = C + (size_t)r * Nc + ocol;
        if (EPI == 3) {
            float4 p = *(const float4*)cp;
            o[0] += p.x; o[1] += p.y; o[2] += p.z; o[3] += p.w;
        }
        *(float4*)cp = make_float4(o[0], o[1], o[2], o[3]);
    }
}

// ---------------- fused msg + CSR aggregation (NO atomics) ----------------
// One wave per dst node; sums silu(Pa[src] + Pb[node] + Pe[p-e0]) over the
// node's sorted-edge range intersected with [e0,e1); u[node] += partial.
// Chunks are serialized on the stream, each node owned by one wave -> race-free.
__global__ void agg_kernel(const float* __restrict__ Pa, const float* __restrict__ Pb,
                           const float* __restrict__ Pe, const int* __restrict__ esrc,
                           const int* __restrict__ rowptr,
                           float* __restrict__ u, int e0, int e1)
{
    int node = blockIdx.x * 4 + (threadIdx.x >> 6);
    if (node >= NN) return;
    int beg = rowptr[node], end = rowptr[node + 1];
    int lo = beg > e0 ? beg : e0;
    int hi = end < e1 ? end : e1;
    if (lo >= hi) return;
    int lane = threadIdx.x & 63;
    int j = lane * 4;
    float4 b = *(const float4*)(Pb + (size_t)node * HH + j);
    float4 acc = make_float4(0.f, 0.f, 0.f, 0.f);
    for (int p = lo; p < hi; ++p) {
        int src = esrc[p];
        float4 a = *(const float4*)(Pa + (size_t)src * HH + j);
        float4 c = *(const float4*)(Pe + (size_t)(p - e0) * HH + j);
        acc.x += silu_f(a.x + b.x + c.x);
        acc.y += silu_f(a.y + b.y + c.y);
        acc.z += silu_f(a.z + b.z + c.z);
        acc.w += silu_f(a.w + b.w + c.w);
    }
    float* up = u + (size_t)node * HH + j;
    float4 uo = *(const float4*)up;
    uo.x += acc.x; uo.y += acc.y; uo.z += acc.z; uo.w += acc.w;
    *(float4*)up = uo;
}

// ---------------- edge_index normalization (int64-vs-int32 autodetect) ----------------
__global__ void detect_kernel(const uint32_t* __restrict__ w, int* flag)
{
    int i = blockIdx.x * 256 + threadIdx.x;
    bool bad = false;
    if (i < NE) {  // only scan first half -> reads stay in-bounds for either layout
        uint32_t lo = w[2 * i], hi = w[2 * i + 1];
        bad = (hi != 0u) || (lo >= (uint32_t)NN);
    }
    if (__any(bad)) {
        if ((threadIdx.x & 63) == 0) atomicAnd(flag, 0);
    }
}
__global__ void convert_kernel(const uint32_t* __restrict__ w, const int* __restrict__ flag,
                               int* __restrict__ out)
{
    int i = blockIdx.x * 256 + threadIdx.x;
    if (i >= 2 * NE) return;
    out[i] = (*flag) ? (int)w[2 * i] : (int)w[i];
}
__global__ void deg_kernel(const int* __restrict__ idx, int* __restrict__ cnt)
{
    int e = blockIdx.x * 256 + threadIdx.x;
    if (e < NE) atomicAdd(cnt + idx[NE + e], 1);
}

// ---------------- exclusive prefix scan of cnt[NN] -> rowptr[NN+1], single block ----------------
__global__ void scan_kernel(const int* __restrict__ cnt, int* __restrict__ rowptr)
{
    __shared__ int part[1024];
    const int T = 1024, PER = (NN + T - 1) / T;  // 20 elems/thread
    int t = threadIdx.x;
    int base = t * PER;
    int s = 0;
    for (int i = 0; i < PER; i++) {
        int idx = base + i;
        if (idx < NN) s += cnt[idx];
    }
    part[t] = s;
    __syncthreads();
    // inclusive Hillis-Steele scan over 1024 partials
    for (int off = 1; off < T; off <<= 1) {
        int v = (t >= off) ? part[t - off] : 0;
        __syncthreads();
        part[t] += v;
        __syncthreads();
    }
    int run = (t == 0) ? 0 : part[t - 1];
    for (int i = 0; i < PER; i++) {
        int idx = base + i;
        if (idx < NN) { rowptr[idx] = run; run += cnt[idx]; }
    }
    if (t == T - 1) rowptr[NN] = part[T - 1];
}

// ---------------- scatter edges into dst-sorted order ----------------
__global__ void fill_kernel(const int* __restrict__ idx, const int* __restrict__ rowptr,
                            int* __restrict__ fillc, int* __restrict__ esrc,
                            int* __restrict__ eorig)
{
    int e = blockIdx.x * 256 + threadIdx.x;
    if (e >= NE) return;
    int dst = idx[NE + e];
    int pos = rowptr[dst] + atomicAdd(fillc + dst, 1);
    esrc[pos]  = idx[e];
    eorig[pos] = e;
}

// ---------------- launcher ----------------
extern "C" void kernel_launch(void* const* d_in, const int* in_sizes, int n_in,
                              void* d_out, int out_size, void* d_ws, size_t ws_size,
                              hipStream_t stream)
{
    const float* node_state = (const float*)d_in[0];
    const float* edge_attr  = (const float*)d_in[1];
    const float* nn_g = (const float*)d_in[2];
    const float* nn_b = (const float*)d_in[3];
    const float* mn_g = (const float*)d_in[4];
    const float* mn_b = (const float*)d_in[5];
    const float* eW1  = (const float*)d_in[6];
    const float* eb1  = (const float*)d_in[7];
    const float* eW2  = (const float*)d_in[8];
    const float* eb2  = (const float*)d_in[9];
    const float* nW1  = (const float*)d_in[10];
    const float* nb1  = (const float*)d_in[11];
    const float* nW2  = (const float*)d_in[12];
    const float* nb2  = (const float*)d_in[13];
    const uint32_t* eidx_raw = (const uint32_t*)d_in[14];

    const size_t SZ = (size_t)NN * HH;           // 5,120,000 floats
    const size_t BIGSZ = (size_t)ECH * HH;       // 20,480,000 floats (>= NN*512)
    float* ws  = (float*)d_ws;
    float* hn  = ws;
    float* Pa  = ws + SZ;
    float* Pb  = ws + 2 * SZ;
    float* u   = ws + 3 * SZ;
    float* agg = ws + 4 * SZ;
    float* big = ws + 5 * SZ;      // Pe chunk, later aliased by z (NN*512)
    float* Pe  = big;
    float* z   = big;
    int* idx32  = (int*)(big + BIGSZ);
    int* esrc   = idx32 + 2 * NE;
    int* eorig  = esrc + NE;
    int* rowptr = eorig + NE;      // NN+1
    int* cnt    = rowptr + NN + 1;
    int* fillc  = cnt + NN;
    int* flag   = fillc + NN;
    size_t needed = ((size_t)(flag + 1) - (size_t)d_ws);
    if (ws_size < needed) return;  // insufficient scratch: fail verification, don't crash

    float* h = (float*)d_out;

    // h <- node_state
    hipMemcpyAsync(h, node_state, SZ * sizeof(float), hipMemcpyDeviceToDevice, stream);

    // ---- preprocessing: normalize edge_index, degree, CSR sort by dst ----
    hipMemsetAsync(flag, 0xFF, sizeof(int), stream);
    detect_kernel<<<(NE + 255) / 256, 256, 0, stream>>>(eidx_raw, flag);
    convert_kernel<<<(2 * NE + 255) / 256, 256, 0, stream>>>(eidx_raw, flag, idx32);
    hipMemsetAsync(cnt, 0, NN * sizeof(int), stream);
    deg_kernel<<<(NE + 255) / 256, 256, 0, stream>>>(idx32, cnt);
    scan_kernel<<<1, 1024, 0, stream>>>(cnt, rowptr);
    hipMemsetAsync(fillc, 0, NN * sizeof(int), stream);
    fill_kernel<<<(NE + 255) / 256, 256, 0, stream>>>(idx32, rowptr, fillc, esrc, eorig);

    const dim3 gN4(313, 4), gN8(313, 8), gPe(ECH / BM, 4);

    for (int s = 0; s < NSTEPS; s++) {
        const float* eW1s = eW1 + (size_t)s * (2 * HH + EDK) * HH;
        const float* Wa = eW1s;
        const float* Wb = eW1s + (size_t)HH * HH;
        const float* Wc = eW1s + (size_t)2 * HH * HH;
        const float* eb1s = eb1 + (size_t)s * HH;
        const float* eW2s = eW2 + (size_t)s * HH * HH;
        const float* eb2s = eb2 + (size_t)s * HH;
        const float* nW1s = nW1 + (size_t)s * 512 * 512;
        const float* nb1s = nb1 + (size_t)s * 512;
        const float* nW2s = nW2 + (size_t)s * 512 * HH;
        const float* nb2s = nb2 + (size_t)s * HH;

        // hn = LN(h)
        ln_kernel<<<NN / 4, 256, 0, stream>>>(h, nn_g + s * HH, nn_b + s * HH, hn, NN);
        // Pa = hn @ Wa ; Pb = hn @ Wb
        gemm_kernel<0, false, false><<<gN4, 256, 0, stream>>>(hn, nullptr, HH, Wa, HH, nullptr, nullptr, nullptr, 0, Pa, NN, HH, HH);
        gemm_kernel<0, false, false><<<gN4, 256, 0, stream>>>(hn, nullptr, HH, Wb, HH, nullptr, nullptr, nullptr, 0, Pb, NN, HH, HH);
        // u = segment_sum over sorted edges of silu(Pa[src]+Pb[dst]+edge_attr@Wc+eb1)
        hipMemsetAsync(u, 0, SZ * sizeof(float), stream);
        for (int c = 0; c < NCHUNK; c++) {
            int e0 = c * ECH, e1 = e0 + ECH;
            // Pe[p] = edge_attr[eorig[e0+p]] @ Wc + eb1   (sorted edge order)
            gemm_kernel<0, false, true><<<gPe, 256, 0, stream>>>(edge_attr, nullptr, EDK, Wc, HH, eb1s, nullptr, eorig, e0, Pe, ECH, HH, EDK);
            agg_kernel<<<(NN + 3) / 4, 256, 0, stream>>>(Pa, Pb, Pe, esrc, rowptr, u, e0, e1);
        }
        // agg = LN((u @ eW2 + cnt*eb2)/max(cnt,1))
        gemm_kernel<2, false, false><<<gN4, 256, 0, stream>>>(u, nullptr, HH, eW2s, HH, eb2s, cnt, nullptr, 0, agg, NN, HH, HH);
        ln_kernel<<<NN / 4, 256, 0, stream>>>(agg, mn_g + s * HH, mn_b + s * HH, agg, NN);
        // z = silu([hn, agg] @ nW1 + nb1)
        gemm_kernel<1, true, false><<<gN8, 256, 0, stream>>>(hn, agg, HH, nW1s, 512, nb1s, nullptr, nullptr, 0, z, NN, 512, 512);
        // h += z @ nW2 + nb2
        gemm_kernel<3, false, false><<<gN4, 256, 0, stream>>>(z, nullptr, 512, nW2s, HH, nb2s, nullptr, nullptr, 0, h, NN, HH, 512);
    }
}

// Round 3
// 1896.266 us; speedup vs baseline: 3.5532x; 1.5665x over previous
//
#include <hip/hip_runtime.h>
#include <hip/hip_bf16.h>
#include <stdint.h>

// Problem constants (from reference)
#define NN 20000     // nodes
#define NE 320000    // edges
#define HH 256       // hidden
#define EDK 64       // edge_dim
#define NSTEPS 4
#define ECH 160000   // edge chunk (Pe buffer sized for one chunk, bf16)
#define NCHUNK 2
#define WSTEP 606208 // bf16 elems of transposed weights per step

typedef __attribute__((ext_vector_type(8))) short bf16x8;
typedef __attribute__((ext_vector_type(4))) float f32x4;

__device__ __forceinline__ float silu_f(float x) { return x / (1.0f + __expf(-x)); }

__device__ __forceinline__ unsigned short f2bf(float f) {
    __hip_bfloat16 h = __float2bfloat16(f);
    return __builtin_bit_cast(unsigned short, h);
}
__device__ __forceinline__ float bf2f(unsigned short u) {
    unsigned int x = ((unsigned int)u) << 16;
    return __builtin_bit_cast(float, x);
}
__device__ __forceinline__ unsigned int pk2(float a, float b) {
    return (unsigned int)f2bf(a) | ((unsigned int)f2bf(b) << 16);
}

// ---------------- LayerNorm: one wave per row of 256 floats ----------------
__global__ void ln_kernel(const float* __restrict__ x, const float* __restrict__ g,
                          const float* __restrict__ b, float* __restrict__ y, int M)
{
    int row  = blockIdx.x * 4 + (threadIdx.x >> 6);
    int lane = threadIdx.x & 63;
    if (row >= M) return;
    float4 v = *(const float4*)(x + (size_t)row * HH + lane * 4);
    float s  = v.x + v.y + v.z + v.w;
    float ss = v.x*v.x + v.y*v.y + v.z*v.z + v.w*v.w;
#pragma unroll
    for (int off = 32; off > 0; off >>= 1) {
        s  += __shfl_down(s, off);
        ss += __shfl_down(ss, off);
    }
    float mean = __shfl(s, 0) * (1.0f / HH);
    float ms   = __shfl(ss, 0) * (1.0f / HH);
    float rstd = rsqrtf(ms - mean * mean + 1e-5f);
    float4 gg = *(const float4*)(g + lane * 4);
    float4 bb = *(const float4*)(b + lane * 4);
    float4 o;
    o.x = (v.x - mean) * rstd * gg.x + bb.x;
    o.y = (v.y - mean) * rstd * gg.y + bb.y;
    o.z = (v.z - mean) * rstd * gg.z + bb.z;
    o.w = (v.w - mean) * rstd * gg.w + bb.w;
    *(float4*)(y + (size_t)row * HH + lane * 4) = o;
}

// ---------------- weight transpose + bf16 convert: all 24 matrices, one launch ----------------
// dst is [N][K] bf16 row-major ("BT") per matrix; 32x32 tiles via LDS.
__global__ void wtr_kernel(const float* __restrict__ eW1, const float* __restrict__ eW2,
                           const float* __restrict__ nW1, const float* __restrict__ nW2,
                           unsigned short* __restrict__ wbuf)
{
    int bx = blockIdx.x;
    int s  = bx / 592, t = bx % 592;
    const float* e1 = eW1 + (size_t)s * 576 * 256;
    unsigned short* wb = wbuf + (size_t)s * WSTEP;
    const float* src; unsigned short* dst; int K, N;
    if      (t < 64)  { src = e1;                          K = 256; N = 256; dst = wb; }
    else if (t < 128) { src = e1 + 65536;                  K = 256; N = 256; dst = wb + 65536;  t -= 64; }
    else if (t < 144) { src = e1 + 131072;                 K = 64;  N = 256; dst = wb + 131072; t -= 128; }
    else if (t < 208) { src = eW2 + (size_t)s * 65536;     K = 256; N = 256; dst = wb + 147456; t -= 144; }
    else if (t < 464) { src = nW1 + (size_t)s * 262144;    K = 512; N = 512; dst = wb + 212992; t -= 208; }
    else              { src = nW2 + (size_t)s * 131072;    K = 512; N = 256; dst = wb + 475136; t -= 464; }
    int ntn = N >> 5;
    int tk = t / ntn, tn = t % ntn;
    int k0 = tk * 32, n0 = tn * 32;
    __shared__ float ts[32][33];
    int tx = threadIdx.x & 31, ty = threadIdx.x >> 5;
#pragma unroll
    for (int i = 0; i < 4; i++)
        ts[ty + i * 8][tx] = src[(size_t)(k0 + ty + i * 8) * N + n0 + tx];
    __syncthreads();
#pragma unroll
    for (int i = 0; i < 4; i++)
        dst[(size_t)(n0 + ty + i * 8) * K + k0 + tx] = f2bf(ts[tx][ty + i * 8]);
}

// ---------------- MFMA bf16 GEMM: C[M,Nc] = A[M,K] @ BT[Nc,K]^T (+epilogue) ----------------
// A is fp32 (converted to bf16 while staging); BT is pre-converted bf16 [Nc][K].
// EPI: 0 = acc+bias   1 = silu(acc+bias)   2 = (acc + cnt*bias)/max(cnt,1)   3 = C += acc+bias
// ASRC: 0 = plain rows (lda)   1 = gathered rows Aidx[rowoff+r] (lda)   2 = concat A|A2 (ld 256 each)
#define GBM 128
#define GBN 128
#define GBK 64
template <int EPI, int ASRC, bool BF16OUT>
__global__ __launch_bounds__(256) void mgemm(
    const float* __restrict__ A, const float* __restrict__ A2, int lda,
    const unsigned short* __restrict__ BT,
    const float* __restrict__ bias, const int* __restrict__ cnt,
    const int* __restrict__ Aidx, int rowoff,
    void* __restrict__ Cout, int M, int Nc, int K)
{
    __shared__ unsigned short lsA[GBM * GBK];
    __shared__ unsigned short lsB[GBN * GBK];
    const int tid = threadIdx.x;
    const int row0 = blockIdx.x * GBM, col0 = blockIdx.y * GBN;
    const int r = tid >> 1, half = tid & 1;      // staging row / half-row
    const int w = tid >> 6, l = tid & 63;        // wave id / lane
    const int wm = w >> 1, wn = w & 1;           // 2x2 wave grid, 64x64 per wave

    int grow = row0 + r;
    bool aval = (grow < M);
    const float* arow = nullptr;
    if (ASRC == 1) { if (aval) arow = A + (size_t)Aidx[rowoff + grow] * lda; }
    else if (ASRC == 0) { if (aval) arow = A + (size_t)grow * lda; }
    const unsigned short* brow = BT + (size_t)(col0 + r) * K;

    f32x4 acc[4][4] = {};

    for (int k0 = 0; k0 < K; k0 += GBK) {
        // ---- stage A: 32 fp32 -> 32 bf16, swizzled 16B chunks ----
        {
            const float* ap = nullptr;
            if (ASRC == 2) {
                if (aval) ap = ((k0 < 256) ? A : A2) + (size_t)grow * 256 + (k0 & 255) + half * 32;
            } else {
                if (aval) ap = arow + k0 + half * 32;
            }
            float4 fv[8];
            if (ap) {
#pragma unroll
                for (int i = 0; i < 8; i++) fv[i] = ((const float4*)ap)[i];
            } else {
#pragma unroll
                for (int i = 0; i < 8; i++) fv[i] = make_float4(0.f, 0.f, 0.f, 0.f);
            }
#pragma unroll
            for (int ci = 0; ci < 4; ci++) {
                uint4 q;
                q.x = pk2(fv[2*ci].x,   fv[2*ci].y);
                q.y = pk2(fv[2*ci].z,   fv[2*ci].w);
                q.z = pk2(fv[2*ci+1].x, fv[2*ci+1].y);
                q.w = pk2(fv[2*ci+1].z, fv[2*ci+1].w);
                int slot = half * 4 + ci;
                int phys = slot ^ (r & 7);
                *(uint4*)&lsA[r * GBK + phys * 8] = q;
            }
        }
        // ---- stage B: straight bf16 copy, same swizzle ----
        {
            const unsigned short* bp = brow + k0 + half * 32;
#pragma unroll
            for (int ci = 0; ci < 4; ci++) {
                uint4 q = ((const uint4*)bp)[ci];
                int slot = half * 4 + ci;
                int phys = slot ^ (r & 7);
                *(uint4*)&lsB[r * GBK + phys * 8] = q;
            }
        }
        __syncthreads();
        // ---- 2 k-steps of 16x16x32 MFMAs ----
#pragma unroll
        for (int ks = 0; ks < 2; ks++) {
            bf16x8 bfr[4];
#pragma unroll
            for (int n = 0; n < 4; n++) {
                int rn = wn * 64 + n * 16 + (l & 15);
                int phys = (ks * 4 + (l >> 4)) ^ (rn & 7);
                bfr[n] = *(bf16x8*)&lsB[rn * GBK + phys * 8];
            }
#pragma unroll
            for (int m = 0; m < 4; m++) {
                int rm = wm * 64 + m * 16 + (l & 15);
                int phys = (ks * 4 + (l >> 4)) ^ (rm & 7);
                bf16x8 af = *(bf16x8*)&lsA[rm * GBK + phys * 8];
#pragma unroll
                for (int n = 0; n < 4; n++)
                    acc[m][n] = __builtin_amdgcn_mfma_f32_16x16x32_bf16(af, bfr[n], acc[m][n], 0, 0, 0);
            }
        }
        __syncthreads();
    }

    // ---- epilogue: C row = (lane>>4)*4 + i, col = lane&15 (verified m89 layout) ----
    float* Cf = (float*)Cout;
    unsigned short* Cb = (unsigned short*)Cout;
    const int cbase = col0 + wn * 64 + (l & 15);
#pragma unroll
    for (int n = 0; n < 4; n++) {
        int c = cbase + n * 16;
        float bv = bias ? bias[c] : 0.0f;
#pragma unroll
        for (int m = 0; m < 4; m++) {
            int rbase = row0 + wm * 64 + m * 16 + (l >> 4) * 4;
#pragma unroll
            for (int i = 0; i < 4; i++) {
                int rr = rbase + i;
                if (rr >= M) continue;
                float o = acc[m][n][i];
                if (EPI == 2) {
                    float cf = (float)cnt[rr];
                    o = (o + cf * bv) / fmaxf(cf, 1.0f);
                } else {
                    o += bv;
                    if (EPI == 1) o = silu_f(o);
                }
                size_t off = (size_t)rr * Nc + c;
                if (EPI == 3)       { Cf[off] += o; }
                else if (BF16OUT)   { Cb[off] = f2bf(o); }
                else                { Cf[off] = o; }
            }
        }
    }
}

// ---------------- fused msg + CSR aggregation (bf16 inputs, fp32 accum, NO atomics) ----------------
__global__ void agg_kernel(const unsigned short* __restrict__ Pa, const unsigned short* __restrict__ Pb,
                           const unsigned short* __restrict__ Pe, const int* __restrict__ esrc,
                           const int* __restrict__ rowptr,
                           float* __restrict__ u, int e0, int e1)
{
    int node = blockIdx.x * 4 + (threadIdx.x >> 6);
    if (node >= NN) return;
    int beg = rowptr[node], end = rowptr[node + 1];
    int lo = beg > e0 ? beg : e0;
    int hi = end < e1 ? end : e1;
    if (lo >= hi) return;
    int lane = threadIdx.x & 63;
    int j = lane * 4;
    ushort4 pb4 = *(const ushort4*)(Pb + (size_t)node * HH + j);
    float b0 = bf2f(pb4.x), b1 = bf2f(pb4.y), b2 = bf2f(pb4.z), b3 = bf2f(pb4.w);
    float a0 = 0.f, a1 = 0.f, a2 = 0.f, a3 = 0.f;
    for (int p = lo; p < hi; ++p) {
        int src = esrc[p];
        ushort4 pa4 = *(const ushort4*)(Pa + (size_t)src * HH + j);
        ushort4 pe4 = *(const ushort4*)(Pe + (size_t)(p - e0) * HH + j);
        a0 += silu_f(bf2f(pa4.x) + b0 + bf2f(pe4.x));
        a1 += silu_f(bf2f(pa4.y) + b1 + bf2f(pe4.y));
        a2 += silu_f(bf2f(pa4.z) + b2 + bf2f(pe4.z));
        a3 += silu_f(bf2f(pa4.w) + b3 + bf2f(pe4.w));
    }
    float* up = u + (size_t)node * HH + j;
    float4 uo = *(const float4*)up;
    uo.x += a0; uo.y += a1; uo.z += a2; uo.w += a3;
    *(float4*)up = uo;
}

// ---------------- edge_index normalization (int64-vs-int32 autodetect) ----------------
__global__ void detect_kernel(const uint32_t* __restrict__ w, int* flag)
{
    int i = blockIdx.x * 256 + threadIdx.x;
    bool bad = false;
    if (i < NE) {
        uint32_t lo = w[2 * i], hi = w[2 * i + 1];
        bad = (hi != 0u) || (lo >= (uint32_t)NN);
    }
    if (__any(bad)) {
        if ((threadIdx.x & 63) == 0) atomicAnd(flag, 0);
    }
}
__global__ void convert_kernel(const uint32_t* __restrict__ w, const int* __restrict__ flag,
                               int* __restrict__ out)
{
    int i = blockIdx.x * 256 + threadIdx.x;
    if (i >= 2 * NE) return;
    out[i] = (*flag) ? (int)w[2 * i] : (int)w[i];
}
__global__ void deg_kernel(const int* __restrict__ idx, int* __restrict__ cnt)
{
    int e = blockIdx.x * 256 + threadIdx.x;
    if (e < NE) atomicAdd(cnt + idx[NE + e], 1);
}

// ---------------- exclusive prefix scan of cnt[NN] -> rowptr[NN+1], single block ----------------
__global__ void scan_kernel(const int* __restrict__ cnt, int* __restrict__ rowptr)
{
    __shared__ int part[1024];
    const int T = 1024, PER = (NN + T - 1) / T;
    int t = threadIdx.x;
    int base = t * PER;
    int s = 0;
    for (int i = 0; i < PER; i++) {
        int idx = base + i;
        if (idx < NN) s += cnt[idx];
    }
    part[t] = s;
    __syncthreads();
    for (int off = 1; off < T; off <<= 1) {
        int v = (t >= off) ? part[t - off] : 0;
        __syncthreads();
        part[t] += v;
        __syncthreads();
    }
    int run = (t == 0) ? 0 : part[t - 1];
    for (int i = 0; i < PER; i++) {
        int idx = base + i;
        if (idx < NN) { rowptr[idx] = run; run += cnt[idx]; }
    }
    if (t == T - 1) rowptr[NN] = part[T - 1];
}

// ---------------- scatter edges into dst-sorted order ----------------
__global__ void fill_kernel(const int* __restrict__ idx, const int* __restrict__ rowptr,
                            int* __restrict__ fillc, int* __restrict__ esrc,
                            int* __restrict__ eorig)
{
    int e = blockIdx.x * 256 + threadIdx.x;
    if (e >= NE) return;
    int dst = idx[NE + e];
    int pos = rowptr[dst] + atomicAdd(fillc + dst, 1);
    esrc[pos]  = idx[e];
    eorig[pos] = e;
}

// ---------------- launcher ----------------
extern "C" void kernel_launch(void* const* d_in, const int* in_sizes, int n_in,
                              void* d_out, int out_size, void* d_ws, size_t ws_size,
                              hipStream_t stream)
{
    const float* node_state = (const float*)d_in[0];
    const float* edge_attr  = (const float*)d_in[1];
    const float* nn_g = (const float*)d_in[2];
    const float* nn_b = (const float*)d_in[3];
    const float* mn_g = (const float*)d_in[4];
    const float* mn_b = (const float*)d_in[5];
    const float* eW1  = (const float*)d_in[6];
    const float* eb1  = (const float*)d_in[7];
    const float* eW2  = (const float*)d_in[8];
    const float* eb2  = (const float*)d_in[9];
    const float* nW1  = (const float*)d_in[10];
    const float* nb1  = (const float*)d_in[11];
    const float* nW2  = (const float*)d_in[12];
    const float* nb2  = (const float*)d_in[13];
    const uint32_t* eidx_raw = (const uint32_t*)d_in[14];

    const size_t SZ = (size_t)NN * HH;                 // 5,120,000
    const size_t BIGBYTES = (size_t)ECH * HH * 2;      // 81,920,000 (>= NN*512*4)
    float* ws   = (float*)d_ws;
    float* hn   = ws;
    float* u    = hn + SZ;
    float* aggb = u + SZ;
    unsigned short* Pa = (unsigned short*)(aggb + SZ);
    unsigned short* Pb = Pa + SZ;
    char* bigc  = (char*)(Pb + SZ);
    unsigned short* Pe = (unsigned short*)bigc;        // ECH*HH bf16
    float* z    = (float*)bigc;                        // NN*512 fp32 (alias, after Pe dead)
    unsigned short* wbuf = (unsigned short*)(bigc + BIGBYTES);
    int* idx32  = (int*)(wbuf + 4 * WSTEP);
    int* esrc   = idx32 + 2 * NE;
    int* eorig  = esrc + NE;
    int* rowptr = eorig + NE;      // NN+1
    int* cnt    = rowptr + NN + 1;
    int* fillc  = cnt + NN;
    int* flag   = fillc + NN;
    size_t needed = ((size_t)(flag + 1) - (size_t)d_ws);
    if (ws_size < needed) return;  // insufficient scratch: fail verification, don't crash

    float* h = (float*)d_out;

    hipMemcpyAsync(h, node_state, SZ * sizeof(float), hipMemcpyDeviceToDevice, stream);

    // ---- preprocessing ----
    wtr_kernel<<<4 * 592, 256, 0, stream>>>(eW1, eW2, nW1, nW2, wbuf);
    hipMemsetAsync(flag, 0xFF, sizeof(int), stream);
    detect_kernel<<<(NE + 255) / 256, 256, 0, stream>>>(eidx_raw, flag);
    convert_kernel<<<(2 * NE + 255) / 256, 256, 0, stream>>>(eidx_raw, flag, idx32);
    hipMemsetAsync(cnt, 0, NN * sizeof(int), stream);
    deg_kernel<<<(NE + 255) / 256, 256, 0, stream>>>(idx32, cnt);
    scan_kernel<<<1, 1024, 0, stream>>>(cnt, rowptr);
    hipMemsetAsync(fillc, 0, NN * sizeof(int), stream);
    fill_kernel<<<(NE + 255) / 256, 256, 0, stream>>>(idx32, rowptr, fillc, esrc, eorig);

    const dim3 gN2((NN + GBM - 1) / GBM, 2);   // Nc=256
    const dim3 gN4((NN + GBM - 1) / GBM, 4);   // Nc=512
    const dim3 gPe(ECH / GBM, 2);

    for (int s = 0; s < NSTEPS; s++) {
        const unsigned short* wb = wbuf + (size_t)s * WSTEP;
        const unsigned short* WaT   = wb;
        const unsigned short* WbT   = wb + 65536;
        const unsigned short* WcT   = wb + 131072;
        const unsigned short* eW2T  = wb + 147456;
        const unsigned short* nW1T  = wb + 212992;
        const unsigned short* nW2T  = wb + 475136;
        const float* eb1s = eb1 + (size_t)s * HH;
        const float* eb2s = eb2 + (size_t)s * HH;
        const float* nb1s = nb1 + (size_t)s * 512;
        const float* nb2s = nb2 + (size_t)s * HH;

        // hn = LN(h)  [fp32]
        ln_kernel<<<NN / 4, 256, 0, stream>>>(h, nn_g + s * HH, nn_b + s * HH, hn, NN);
        // Pa = bf16(hn @ Wa) ; Pb = bf16(hn @ Wb)
        mgemm<0, 0, true><<<gN2, 256, 0, stream>>>(hn, nullptr, HH, WaT, nullptr, nullptr, nullptr, 0, Pa, NN, HH, HH);
        mgemm<0, 0, true><<<gN2, 256, 0, stream>>>(hn, nullptr, HH, WbT, nullptr, nullptr, nullptr, 0, Pb, NN, HH, HH);
        // u = segment_sum over sorted edges of silu(Pa[src]+Pb[dst]+edge_attr@Wc+eb1)
        hipMemsetAsync(u, 0, SZ * sizeof(float), stream);
        for (int c = 0; c < NCHUNK; c++) {
            int e0 = c * ECH, e1 = e0 + ECH;
            mgemm<0, 1, true><<<gPe, 256, 0, stream>>>(edge_attr, nullptr, EDK, WcT, eb1s, nullptr, eorig, e0, Pe, ECH, HH, EDK);
            agg_kernel<<<(NN + 3) / 4, 256, 0, stream>>>(Pa, Pb, Pe, esrc, rowptr, u, e0, e1);
        }
        // aggb = LN((u @ eW2 + cnt*eb2)/max(cnt,1))
        mgemm<2, 0, false><<<gN2, 256, 0, stream>>>(u, nullptr, HH, eW2T, eb2s, cnt, nullptr, 0, aggb, NN, HH, HH);
        ln_kernel<<<NN / 4, 256, 0, stream>>>(aggb, mn_g + s * HH, mn_b + s * HH, aggb, NN);
        // z = silu([hn, aggb] @ nW1 + nb1)
        mgemm<1, 2, false><<<gN4, 256, 0, stream>>>(hn, aggb, HH, nW1T, nb1s, nullptr, nullptr, 0, z, NN, 512, 512);
        // h += z @ nW2 + nb2
        mgemm<3, 0, false><<<gN2, 256, 0, stream>>>(z, nullptr, 512, nW2T, nb2s, nullptr, nullptr, 0, h, NN, HH, 512);
    }
}

// Round 4
// 1855.132 us; speedup vs baseline: 3.6320x; 1.0222x over previous
//
#include <hip/hip_runtime.h>
#include <hip/hip_bf16.h>
#include <stdint.h>

// Problem constants (from reference)
#define NN 20000     // nodes
#define NE 320000    // edges
#define HH 256       // hidden
#define EDK 64       // edge_dim
#define NSTEPS 4
#define ECH 80000    // edges per chunk (Pe buffer covers one chunk)
#define NCHUNK 4
#define WSTEP 606208 // bf16 elems of transposed weights per step

typedef __attribute__((ext_vector_type(8))) short bf16x8;
typedef __attribute__((ext_vector_type(4))) float f32x4;

__device__ __forceinline__ float silu_f(float x) { return x / (1.0f + __expf(-x)); }

__device__ __forceinline__ unsigned short f2bf(float f) {
    __hip_bfloat16 h = __float2bfloat16(f);
    return __builtin_bit_cast(unsigned short, h);
}
__device__ __forceinline__ float bf2f(unsigned short u) {
    unsigned int x = ((unsigned int)u) << 16;
    return __builtin_bit_cast(float, x);
}
__device__ __forceinline__ unsigned int pk2(float a, float b) {
    return (unsigned int)f2bf(a) | ((unsigned int)f2bf(b) << 16);
}

// ---------------- LayerNorm: one wave per row of 256 floats ----------------
__global__ void ln_kernel(const float* __restrict__ x, const float* __restrict__ g,
                          const float* __restrict__ b, float* __restrict__ y, int M)
{
    int row  = blockIdx.x * 4 + (threadIdx.x >> 6);
    int lane = threadIdx.x & 63;
    if (row >= M) return;
    float4 v = *(const float4*)(x + (size_t)row * HH + lane * 4);
    float s  = v.x + v.y + v.z + v.w;
    float ss = v.x*v.x + v.y*v.y + v.z*v.z + v.w*v.w;
#pragma unroll
    for (int off = 32; off > 0; off >>= 1) {
        s  += __shfl_down(s, off);
        ss += __shfl_down(ss, off);
    }
    float mean = __shfl(s, 0) * (1.0f / HH);
    float ms   = __shfl(ss, 0) * (1.0f / HH);
    float rstd = rsqrtf(ms - mean * mean + 1e-5f);
    float4 gg = *(const float4*)(g + lane * 4);
    float4 bb = *(const float4*)(b + lane * 4);
    float4 o;
    o.x = (v.x - mean) * rstd * gg.x + bb.x;
    o.y = (v.y - mean) * rstd * gg.y + bb.y;
    o.z = (v.z - mean) * rstd * gg.z + bb.z;
    o.w = (v.w - mean) * rstd * gg.w + bb.w;
    *(float4*)(y + (size_t)row * HH + lane * 4) = o;
}

// ---------------- weight transpose + bf16 convert: all 24 matrices, one launch ----------------
// dst is [N][K] bf16 row-major ("BT") per matrix; 32x32 tiles via LDS.
__global__ void wtr_kernel(const float* __restrict__ eW1, const float* __restrict__ eW2,
                           const float* __restrict__ nW1, const float* __restrict__ nW2,
                           unsigned short* __restrict__ wbuf)
{
    int bx = blockIdx.x;
    int s  = bx / 592, t = bx % 592;
    const float* e1 = eW1 + (size_t)s * 576 * 256;
    unsigned short* wb = wbuf + (size_t)s * WSTEP;
    const float* src; unsigned short* dst; int K, N;
    if      (t < 64)  { src = e1;                          K = 256; N = 256; dst = wb; }
    else if (t < 128) { src = e1 + 65536;                  K = 256; N = 256; dst = wb + 65536;  t -= 64; }
    else if (t < 144) { src = e1 + 131072;                 K = 64;  N = 256; dst = wb + 131072; t -= 128; }
    else if (t < 208) { src = eW2 + (size_t)s * 65536;     K = 256; N = 256; dst = wb + 147456; t -= 144; }
    else if (t < 464) { src = nW1 + (size_t)s * 262144;    K = 512; N = 512; dst = wb + 212992; t -= 208; }
    else              { src = nW2 + (size_t)s * 131072;    K = 512; N = 256; dst = wb + 475136; t -= 464; }
    int ntn = N >> 5;
    int tk = t / ntn, tn = t % ntn;
    int k0 = tk * 32, n0 = tn * 32;
    __shared__ float ts[32][33];
    int tx = threadIdx.x & 31, ty = threadIdx.x >> 5;
#pragma unroll
    for (int i = 0; i < 4; i++)
        ts[ty + i * 8][tx] = src[(size_t)(k0 + ty + i * 8) * N + n0 + tx];
    __syncthreads();
#pragma unroll
    for (int i = 0; i < 4; i++)
        dst[(size_t)(n0 + ty + i * 8) * K + k0 + tx] = f2bf(ts[tx][ty + i * 8]);
}

// ---------------- edge_attr gather-to-sorted-order + bf16 convert (once per launch) ----------------
__global__ void easort_kernel(const float* __restrict__ ea, const int* __restrict__ eorig,
                              unsigned short* __restrict__ out)
{
    int gid = blockIdx.x * 256 + threadIdx.x;
    int p = gid >> 4, q = gid & 15;
    if (p >= NE) return;
    float4 v = *(const float4*)(ea + (size_t)eorig[p] * EDK + q * 4);
    ushort4 o;
    o.x = f2bf(v.x); o.y = f2bf(v.y); o.z = f2bf(v.z); o.w = f2bf(v.w);
    *(ushort4*)(out + (size_t)p * EDK + q * 4) = o;
}

// ---------------- MFMA bf16 GEMM: C[M,Nc] = A[M,K] @ BT[Nc,K]^T (+epilogue) ----------------
// EPI: 0 = acc+bias   1 = silu(acc+bias)   2 = (acc + cnt*bias)/max(cnt,1)   3 = C += acc+bias
// ASRC: 0 = fp32 rows (lda)   2 = concat fp32 A|A2 (ld 256 each)   3 = bf16 rows (lda)
#define GBM 128
#define GBN 128
#define GBK 64
template <int EPI, int ASRC, bool BF16OUT>
__global__ __launch_bounds__(256) void mgemm(
    const void* __restrict__ A, const float* __restrict__ A2, int lda,
    const unsigned short* __restrict__ BT,
    const float* __restrict__ bias, const int* __restrict__ cnt,
    void* __restrict__ Cout, int M, int Nc, int K)
{
    __shared__ unsigned short smem[GBM * GBK + GBN * GBK];  // 32 KB; reused by bf16 epilogue
    unsigned short* lsA = smem;
    unsigned short* lsB = smem + GBM * GBK;
    const int tid = threadIdx.x;
    const int row0 = blockIdx.x * GBM, col0 = blockIdx.y * GBN;
    const int r = tid >> 1, half = tid & 1;      // staging row / half-row
    const int w = tid >> 6, l = tid & 63;        // wave id / lane
    const int wm = w >> 1, wn = w & 1;           // 2x2 wave grid, 64x64 per wave

    const float* Af = (const float*)A;
    const unsigned short* Ab = (const unsigned short*)A;
    int grow = row0 + r;
    bool aval = (grow < M);
    const unsigned short* brow = BT + (size_t)(col0 + r) * K;

    f32x4 acc[4][4] = {};

    for (int k0 = 0; k0 < K; k0 += GBK) {
        // ---- stage A ----
        if constexpr (ASRC == 3) {
            uint4 q[4] = {};
            if (aval) {
                const unsigned short* ap = Ab + (size_t)grow * lda + k0 + half * 32;
#pragma unroll
                for (int ci = 0; ci < 4; ci++) q[ci] = ((const uint4*)ap)[ci];
            }
#pragma unroll
            for (int ci = 0; ci < 4; ci++) {
                int slot = half * 4 + ci;
                int phys = slot ^ (r & 7);
                *(uint4*)&lsA[r * GBK + phys * 8] = q[ci];
            }
        } else {
            const float* ap = nullptr;
            if constexpr (ASRC == 2) {
                if (aval) ap = ((k0 < 256) ? Af : A2) + (size_t)grow * 256 + (k0 & 255) + half * 32;
            } else {
                if (aval) ap = Af + (size_t)grow * lda + k0 + half * 32;
            }
            float4 fv[8];
            if (ap) {
#pragma unroll
                for (int i = 0; i < 8; i++) fv[i] = ((const float4*)ap)[i];
            } else {
#pragma unroll
                for (int i = 0; i < 8; i++) fv[i] = make_float4(0.f, 0.f, 0.f, 0.f);
            }
#pragma unroll
            for (int ci = 0; ci < 4; ci++) {
                uint4 q;
                q.x = pk2(fv[2*ci].x,   fv[2*ci].y);
                q.y = pk2(fv[2*ci].z,   fv[2*ci].w);
                q.z = pk2(fv[2*ci+1].x, fv[2*ci+1].y);
                q.w = pk2(fv[2*ci+1].z, fv[2*ci+1].w);
                int slot = half * 4 + ci;
                int phys = slot ^ (r & 7);
                *(uint4*)&lsA[r * GBK + phys * 8] = q;
            }
        }
        // ---- stage B: straight bf16 copy, same swizzle ----
        {
            const unsigned short* bp = brow + k0 + half * 32;
#pragma unroll
            for (int ci = 0; ci < 4; ci++) {
                uint4 q = ((const uint4*)bp)[ci];
                int slot = half * 4 + ci;
                int phys = slot ^ (r & 7);
                *(uint4*)&lsB[r * GBK + phys * 8] = q;
            }
        }
        __syncthreads();
        // ---- 2 k-steps of 16x16x32 MFMAs ----
#pragma unroll
        for (int ks = 0; ks < 2; ks++) {
            bf16x8 bfr[4];
#pragma unroll
            for (int n = 0; n < 4; n++) {
                int rn = wn * 64 + n * 16 + (l & 15);
                int phys = (ks * 4 + (l >> 4)) ^ (rn & 7);
                bfr[n] = *(bf16x8*)&lsB[rn * GBK + phys * 8];
            }
#pragma unroll
            for (int m = 0; m < 4; m++) {
                int rm = wm * 64 + m * 16 + (l & 15);
                int phys = (ks * 4 + (l >> 4)) ^ (rm & 7);
                bf16x8 af = *(bf16x8*)&lsA[rm * GBK + phys * 8];
#pragma unroll
                for (int n = 0; n < 4; n++)
                    acc[m][n] = __builtin_amdgcn_mfma_f32_16x16x32_bf16(af, bfr[n], acc[m][n], 0, 0, 0);
            }
        }
        __syncthreads();
    }

    // ---- epilogue: acc row = (lane>>4)*4 + i, col = lane&15 ----
    if constexpr (BF16OUT) {
        // stage to LDS ([128][128] bf16, 16B-chunk XOR swizzle), then stream out 16B stores
        unsigned short* Cb = (unsigned short*)Cout;
#pragma unroll
        for (int n = 0; n < 4; n++) {
            int cl = wn * 64 + n * 16 + (l & 15);
            float bv = bias ? bias[col0 + cl] : 0.0f;
#pragma unroll
            for (int m = 0; m < 4; m++) {
                int rbase = wm * 64 + m * 16 + (l >> 4) * 4;
#pragma unroll
                for (int i = 0; i < 4; i++) {
                    int rl = rbase + i;
                    float o = acc[m][n][i] + bv;
                    if (EPI == 1) o = silu_f(o);
                    int chunk = cl >> 3;
                    int phys = chunk ^ (rl & 15);
                    smem[rl * 128 + phys * 8 + (cl & 7)] = f2bf(o);
                }
            }
        }
        __syncthreads();
        int orow = tid >> 1, hf = tid & 1;
        int rr = row0 + orow;
        if (rr < M) {
            unsigned short* crow = Cb + (size_t)rr * Nc + col0;
#pragma unroll
            for (int c8 = 0; c8 < 8; c8++) {
                int chunk = hf * 8 + c8;
                int phys = chunk ^ (orow & 15);
                uint4 v = *(uint4*)&smem[orow * 128 + phys * 8];
                *(uint4*)(crow + chunk * 8) = v;
            }
        }
    } else {
        float* Cf = (float*)Cout;
        const int cbase = col0 + wn * 64 + (l & 15);
#pragma unroll
        for (int n = 0; n < 4; n++) {
            int c = cbase + n * 16;
            float bv = bias ? bias[c] : 0.0f;
#pragma unroll
            for (int m = 0; m < 4; m++) {
                int rbase = row0 + wm * 64 + m * 16 + (l >> 4) * 4;
#pragma unroll
                for (int i = 0; i < 4; i++) {
                    int rr = rbase + i;
                    if (rr >= M) continue;
                    float o = acc[m][n][i];
                    if (EPI == 2) {
                        float cf = (float)cnt[rr];
                        o = (o + cf * bv) / fmaxf(cf, 1.0f);
                    } else {
                        o += bv;
                        if (EPI == 1) o = silu_f(o);
                    }
                    size_t off = (size_t)rr * Nc + c;
                    if (EPI == 3) Cf[off] += o;
                    else          Cf[off] = o;
                }
            }
        }
    }
}

// ---------------- fused msg + CSR aggregation (bf16 inputs, fp32 accum, NO atomics) ----------------
// Pab[node][512]: cols 0-255 = Pa (src term), cols 256-511 = Pb (dst term)
__global__ void agg_kernel(const unsigned short* __restrict__ Pab,
                           const unsigned short* __restrict__ Pe, const int* __restrict__ esrc,
                           const int* __restrict__ rowptr,
                           float* __restrict__ u, int e0, int e1)
{
    int node = blockIdx.x * 4 + (threadIdx.x >> 6);
    if (node >= NN) return;
    int beg = rowptr[node], end = rowptr[node + 1];
    int lo = beg > e0 ? beg : e0;
    int hi = end < e1 ? end : e1;
    if (lo >= hi) return;
    int lane = threadIdx.x & 63;
    int j = lane * 4;
    ushort4 pb4 = *(const ushort4*)(Pab + (size_t)node * 512 + 256 + j);
    float b0 = bf2f(pb4.x), b1 = bf2f(pb4.y), b2 = bf2f(pb4.z), b3 = bf2f(pb4.w);
    float a0 = 0.f, a1 = 0.f, a2 = 0.f, a3 = 0.f;
    int src_n = esrc[lo];
    for (int p = lo; p < hi; ++p) {
        int src = src_n;
        if (p + 1 < hi) src_n = esrc[p + 1];
        ushort4 pa4 = *(const ushort4*)(Pab + (size_t)src * 512 + j);
        ushort4 pe4 = *(const ushort4*)(Pe + (size_t)(p - e0) * HH + j);
        a0 += silu_f(bf2f(pa4.x) + b0 + bf2f(pe4.x));
        a1 += silu_f(bf2f(pa4.y) + b1 + bf2f(pe4.y));
        a2 += silu_f(bf2f(pa4.z) + b2 + bf2f(pe4.z));
        a3 += silu_f(bf2f(pa4.w) + b3 + bf2f(pe4.w));
    }
    float* up = u + (size_t)node * HH + j;
    float4 uo = *(const float4*)up;
    uo.x += a0; uo.y += a1; uo.z += a2; uo.w += a3;
    *(float4*)up = uo;
}

// ---------------- edge_index normalization (int64-vs-int32 autodetect) ----------------
__global__ void detect_kernel(const uint32_t* __restrict__ w, int* flag)
{
    int i = blockIdx.x * 256 + threadIdx.x;
    bool bad = false;
    if (i < NE) {
        uint32_t lo = w[2 * i], hi = w[2 * i + 1];
        bad = (hi != 0u) || (lo >= (uint32_t)NN);
    }
    if (__any(bad)) {
        if ((threadIdx.x & 63) == 0) atomicAnd(flag, 0);
    }
}
__global__ void convert_kernel(const uint32_t* __restrict__ w, const int* __restrict__ flag,
                               int* __restrict__ out)
{
    int i = blockIdx.x * 256 + threadIdx.x;
    if (i >= 2 * NE) return;
    out[i] = (*flag) ? (int)w[2 * i] : (int)w[i];
}
__global__ void deg_kernel(const int* __restrict__ idx, int* __restrict__ cnt)
{
    int e = blockIdx.x * 256 + threadIdx.x;
    if (e < NE) atomicAdd(cnt + idx[NE + e], 1);
}

// ---------------- exclusive prefix scan of cnt[NN] -> rowptr[NN+1], single block ----------------
__global__ void scan_kernel(const int* __restrict__ cnt, int* __restrict__ rowptr)
{
    __shared__ int part[1024];
    const int T = 1024, PER = (NN + T - 1) / T;
    int t = threadIdx.x;
    int base = t * PER;
    int s = 0;
    for (int i = 0; i < PER; i++) {
        int idx = base + i;
        if (idx < NN) s += cnt[idx];
    }
    part[t] = s;
    __syncthreads();
    for (int off = 1; off < T; off <<= 1) {
        int v = (t >= off) ? part[t - off] : 0;
        __syncthreads();
        part[t] += v;
        __syncthreads();
    }
    int run = (t == 0) ? 0 : part[t - 1];
    for (int i = 0; i < PER; i++) {
        int idx = base + i;
        if (idx < NN) { rowptr[idx] = run; run += cnt[idx]; }
    }
    if (t == T - 1) rowptr[NN] = part[T - 1];
}

// ---------------- scatter edges into dst-sorted order ----------------
__global__ void fill_kernel(const int* __restrict__ idx, const int* __restrict__ rowptr,
                            int* __restrict__ fillc, int* __restrict__ esrc,
                            int* __restrict__ eorig)
{
    int e = blockIdx.x * 256 + threadIdx.x;
    if (e >= NE) return;
    int dst = idx[NE + e];
    int pos = rowptr[dst] + atomicAdd(fillc + dst, 1);
    esrc[pos]  = idx[e];
    eorig[pos] = e;
}

// ---------------- launcher ----------------
extern "C" void kernel_launch(void* const* d_in, const int* in_sizes, int n_in,
                              void* d_out, int out_size, void* d_ws, size_t ws_size,
                              hipStream_t stream)
{
    const float* node_state = (const float*)d_in[0];
    const float* edge_attr  = (const float*)d_in[1];
    const float* nn_g = (const float*)d_in[2];
    const float* nn_b = (const float*)d_in[3];
    const float* mn_g = (const float*)d_in[4];
    const float* mn_b = (const float*)d_in[5];
    const float* eW1  = (const float*)d_in[6];
    const float* eb1  = (const float*)d_in[7];
    const float* eW2  = (const float*)d_in[8];
    const float* eb2  = (const float*)d_in[9];
    const float* nW1  = (const float*)d_in[10];
    const float* nb1  = (const float*)d_in[11];
    const float* nW2  = (const float*)d_in[12];
    const float* nb2  = (const float*)d_in[13];
    const uint32_t* eidx_raw = (const uint32_t*)d_in[14];

    const size_t SZ = (size_t)NN * HH;                 // 5,120,000
    float* hn = (float*)d_ws;                          // SZ fp32
    float* u  = hn + SZ;                               // SZ fp32
    unsigned short* Pab = (unsigned short*)(u + SZ);   // NN*512 bf16
    unsigned short* eas = Pab + (size_t)NN * 512;      // NE*EDK bf16 (sorted edge_attr)
    unsigned short* Pe  = eas + (size_t)NE * EDK;      // ECH*HH bf16 (41 MB)
    float* aggb = (float*)Pe;                                              // alias: NN*HH fp32
    unsigned short* zb = (unsigned short*)((char*)Pe + (size_t)NN * HH * 4); // alias: NN*512 bf16
    unsigned short* wbuf = Pe + (size_t)ECH * HH;
    int* idx32  = (int*)(wbuf + 4 * WSTEP);
    int* esrc   = idx32 + 2 * NE;
    int* eorig  = esrc + NE;
    int* rowptr = eorig + NE;      // NN+1
    int* cnt    = rowptr + NN + 1;
    int* fillc  = cnt + NN;
    int* flag   = fillc + NN;
    size_t needed = ((size_t)(flag + 1) - (size_t)d_ws);
    if (ws_size < needed) return;  // insufficient scratch: fail verification, don't crash

    float* h = (float*)d_out;

    hipMemcpyAsync(h, node_state, SZ * sizeof(float), hipMemcpyDeviceToDevice, stream);

    // ---- preprocessing ----
    wtr_kernel<<<4 * 592, 256, 0, stream>>>(eW1, eW2, nW1, nW2, wbuf);
    hipMemsetAsync(flag, 0xFF, sizeof(int), stream);
    detect_kernel<<<(NE + 255) / 256, 256, 0, stream>>>(eidx_raw, flag);
    convert_kernel<<<(2 * NE + 255) / 256, 256, 0, stream>>>(eidx_raw, flag, idx32);
    hipMemsetAsync(cnt, 0, NN * sizeof(int), stream);
    deg_kernel<<<(NE + 255) / 256, 256, 0, stream>>>(idx32, cnt);
    scan_kernel<<<1, 1024, 0, stream>>>(cnt, rowptr);
    hipMemsetAsync(fillc, 0, NN * sizeof(int), stream);
    fill_kernel<<<(NE + 255) / 256, 256, 0, stream>>>(idx32, rowptr, fillc, esrc, eorig);
    easort_kernel<<<(NE * 16) / 256, 256, 0, stream>>>(edge_attr, eorig, eas);

    const dim3 gN2((NN + GBM - 1) / GBM, 2);   // Nc=256
    const dim3 gN4((NN + GBM - 1) / GBM, 4);   // Nc=512
    const dim3 gPe(ECH / GBM, 2);

    for (int s = 0; s < NSTEPS; s++) {
        const unsigned short* wb = wbuf + (size_t)s * WSTEP;
        const unsigned short* WabT = wb;            // [512][256]: Wa^T rows 0-255, Wb^T rows 256-511
        const unsigned short* WcT  = wb + 131072;   // [256][64]
        const unsigned short* eW2T = wb + 147456;   // [256][256]
        const unsigned short* nW1T = wb + 212992;   // [512][512]
        const unsigned short* nW2T = wb + 475136;   // [256][512]
        const float* eb1s = eb1 + (size_t)s * HH;
        const float* eb2s = eb2 + (size_t)s * HH;
        const float* nb1s = nb1 + (size_t)s * 512;
        const float* nb2s = nb2 + (size_t)s * HH;

        // hn = LN(h)  [fp32]
        ln_kernel<<<NN / 4, 256, 0, stream>>>(h, nn_g + s * HH, nn_b + s * HH, hn, NN);
        // Pab = bf16(hn @ [Wa|Wb])  (one GEMM, Nc=512)
        mgemm<0, 0, true><<<gN4, 256, 0, stream>>>(hn, nullptr, HH, WabT, nullptr, nullptr, Pab, NN, 512, HH);
        // u = segment_sum over sorted edges of silu(Pa[src]+Pb[dst]+ea_sorted@Wc+eb1)
        hipMemsetAsync(u, 0, SZ * sizeof(float), stream);
        for (int c = 0; c < NCHUNK; c++) {
            int e0 = c * ECH, e1 = e0 + ECH;
            // Pe[p] = ea_sorted[e0+p] @ Wc + eb1   (coalesced bf16 reads, sorted order)
            mgemm<0, 3, true><<<gPe, 256, 0, stream>>>(eas + (size_t)e0 * EDK, nullptr, EDK, WcT, eb1s, nullptr, Pe, ECH, HH, EDK);
            agg_kernel<<<(NN + 3) / 4, 256, 0, stream>>>(Pab, Pe, esrc, rowptr, u, e0, e1);
        }
        // aggb = LN((u @ eW2 + cnt*eb2)/max(cnt,1))
        mgemm<2, 0, false><<<gN2, 256, 0, stream>>>(u, nullptr, HH, eW2T, eb2s, cnt, aggb, NN, HH, HH);
        ln_kernel<<<NN / 4, 256, 0, stream>>>(aggb, mn_g + s * HH, mn_b + s * HH, aggb, NN);
        // zb = bf16(silu([hn, aggb] @ nW1 + nb1))
        mgemm<1, 2, true><<<gN4, 256, 0, stream>>>(hn, aggb, HH, nW1T, nb1s, nullptr, zb, NN, 512, 512);
        // h += zb @ nW2 + nb2
        mgemm<3, 3, false><<<gN2, 256, 0, stream>>>(zb, nullptr, 512, nW2T, nb2s, nullptr, h, NN, HH, 512);
    }
}

// Round 5
// 1689.603 us; speedup vs baseline: 3.9878x; 1.0980x over previous
//
#include <hip/hip_runtime.h>
#include <hip/hip_bf16.h>
#include <stdint.h>

// Problem constants (from reference)
#define NN 20000     // nodes
#define NE 320000    // edges
#define HH 256       // hidden
#define EDK 64       // edge_dim
#define NSTEPS 4
#define ECH 160000   // edges per chunk (Pe buffer covers one chunk)
#define NCHUNK 2
#define WSTEP 606208 // bf16 elems of transposed weights per step

typedef __attribute__((ext_vector_type(8))) short bf16x8;
typedef __attribute__((ext_vector_type(4))) float f32x4;

__device__ __forceinline__ float silu_f(float x) { return x / (1.0f + __expf(-x)); }

__device__ __forceinline__ unsigned short f2bf(float f) {
    __hip_bfloat16 h = __float2bfloat16(f);
    return __builtin_bit_cast(unsigned short, h);
}
__device__ __forceinline__ float bf2f(unsigned short u) {
    unsigned int x = ((unsigned int)u) << 16;
    return __builtin_bit_cast(float, x);
}
__device__ __forceinline__ unsigned int pk2(float a, float b) {
    return (unsigned int)f2bf(a) | ((unsigned int)f2bf(b) << 16);
}

// ---------------- LayerNorm: fp32 in, bf16 out; one wave per row of 256 ----------------
__global__ void ln_kernel(const float* __restrict__ x, const float* __restrict__ g,
                          const float* __restrict__ b, unsigned short* __restrict__ y, int M)
{
    int row  = blockIdx.x * 4 + (threadIdx.x >> 6);
    int lane = threadIdx.x & 63;
    if (row >= M) return;
    float4 v = *(const float4*)(x + (size_t)row * HH + lane * 4);
    float s  = v.x + v.y + v.z + v.w;
    float ss = v.x*v.x + v.y*v.y + v.z*v.z + v.w*v.w;
#pragma unroll
    for (int off = 32; off > 0; off >>= 1) {
        s  += __shfl_down(s, off);
        ss += __shfl_down(ss, off);
    }
    float mean = __shfl(s, 0) * (1.0f / HH);
    float ms   = __shfl(ss, 0) * (1.0f / HH);
    float rstd = rsqrtf(ms - mean * mean + 1e-5f);
    float4 gg = *(const float4*)(g + lane * 4);
    float4 bb = *(const float4*)(b + lane * 4);
    ushort4 o;
    o.x = f2bf((v.x - mean) * rstd * gg.x + bb.x);
    o.y = f2bf((v.y - mean) * rstd * gg.y + bb.y);
    o.z = f2bf((v.z - mean) * rstd * gg.z + bb.z);
    o.w = f2bf((v.w - mean) * rstd * gg.w + bb.w);
    *(ushort4*)(y + (size_t)row * HH + lane * 4) = o;
}

// ---------------- weight transpose + bf16 convert: all 24 matrices, one launch ----------------
__global__ void wtr_kernel(const float* __restrict__ eW1, const float* __restrict__ eW2,
                           const float* __restrict__ nW1, const float* __restrict__ nW2,
                           unsigned short* __restrict__ wbuf)
{
    int bx = blockIdx.x;
    int s  = bx / 592, t = bx % 592;
    const float* e1 = eW1 + (size_t)s * 576 * 256;
    unsigned short* wb = wbuf + (size_t)s * WSTEP;
    const float* src; unsigned short* dst; int K, N;
    if      (t < 64)  { src = e1;                          K = 256; N = 256; dst = wb; }
    else if (t < 128) { src = e1 + 65536;                  K = 256; N = 256; dst = wb + 65536;  t -= 64; }
    else if (t < 144) { src = e1 + 131072;                 K = 64;  N = 256; dst = wb + 131072; t -= 128; }
    else if (t < 208) { src = eW2 + (size_t)s * 65536;     K = 256; N = 256; dst = wb + 147456; t -= 144; }
    else if (t < 464) { src = nW1 + (size_t)s * 262144;    K = 512; N = 512; dst = wb + 212992; t -= 208; }
    else              { src = nW2 + (size_t)s * 131072;    K = 512; N = 256; dst = wb + 475136; t -= 464; }
    int ntn = N >> 5;
    int tk = t / ntn, tn = t % ntn;
    int k0 = tk * 32, n0 = tn * 32;
    __shared__ float ts[32][33];
    int tx = threadIdx.x & 31, ty = threadIdx.x >> 5;
#pragma unroll
    for (int i = 0; i < 4; i++)
        ts[ty + i * 8][tx] = src[(size_t)(k0 + ty + i * 8) * N + n0 + tx];
    __syncthreads();
#pragma unroll
    for (int i = 0; i < 4; i++)
        dst[(size_t)(n0 + ty + i * 8) * K + k0 + tx] = f2bf(ts[tx][ty + i * 8]);
}

// ---------------- edge_attr gather-to-sorted-order + bf16 convert (once per launch) ----------------
__global__ void easort_kernel(const float* __restrict__ ea, const int* __restrict__ eorig,
                              unsigned short* __restrict__ out)
{
    int gid = blockIdx.x * 256 + threadIdx.x;
    int p = gid >> 4, q = gid & 15;
    if (p >= NE) return;
    float4 v = *(const float4*)(ea + (size_t)eorig[p] * EDK + q * 4);
    ushort4 o;
    o.x = f2bf(v.x); o.y = f2bf(v.y); o.z = f2bf(v.z); o.w = f2bf(v.w);
    *(ushort4*)(out + (size_t)p * EDK + q * 4) = o;
}

// ---------------- MFMA bf16 GEMM: C[M,Nc] = A[M,K] @ BT[Nc,K]^T (+epilogue) ----------------
// EPI: 0 = acc+bias   1 = silu(acc+bias)   2 = (acc + cnt*bias)/max(cnt,1)   3 = C += acc+bias
// ASRC: 0 = fp32 rows (lda)   3 = bf16 rows (lda)   4 = concat bf16 A|A2 (ld 256 each)
#define GBM 128
#define GBN 128
#define GBK 64
template <int EPI, int ASRC, bool BF16OUT>
__global__ __launch_bounds__(256) void mgemm(
    const void* __restrict__ A, const void* __restrict__ A2, int lda,
    const unsigned short* __restrict__ BT,
    const float* __restrict__ bias, const int* __restrict__ cnt,
    void* __restrict__ Cout, int M, int Nc, int K)
{
    __shared__ unsigned short smem[GBM * GBK + GBN * GBK];  // 32 KB; reused by bf16 epilogue
    unsigned short* lsA = smem;
    unsigned short* lsB = smem + GBM * GBK;
    const int tid = threadIdx.x;
    const int row0 = blockIdx.x * GBM, col0 = blockIdx.y * GBN;
    const int r = tid >> 1, half = tid & 1;      // staging row / half-row
    const int w = tid >> 6, l = tid & 63;        // wave id / lane
    const int wm = w >> 1, wn = w & 1;           // 2x2 wave grid, 64x64 per wave

    const float* Af = (const float*)A;
    const unsigned short* Ab = (const unsigned short*)A;
    const unsigned short* A2b = (const unsigned short*)A2;
    int grow = row0 + r;
    bool aval = (grow < M);
    const unsigned short* brow = BT + (size_t)(col0 + r) * K;

    f32x4 acc[4][4] = {};

    for (int k0 = 0; k0 < K; k0 += GBK) {
        // ---- stage A ----
        if constexpr (ASRC == 3 || ASRC == 4) {
            uint4 q[4] = {};
            if (aval) {
                const unsigned short* ap;
                if constexpr (ASRC == 4)
                    ap = ((k0 < 256) ? Ab : A2b) + (size_t)grow * 256 + (k0 & 255) + half * 32;
                else
                    ap = Ab + (size_t)grow * lda + k0 + half * 32;
#pragma unroll
                for (int ci = 0; ci < 4; ci++) q[ci] = ((const uint4*)ap)[ci];
            }
#pragma unroll
            for (int ci = 0; ci < 4; ci++) {
                int slot = half * 4 + ci;
                int phys = slot ^ (r & 7);
                *(uint4*)&lsA[r * GBK + phys * 8] = q[ci];
            }
        } else {
            float4 fv[8];
            if (aval) {
                const float* ap = Af + (size_t)grow * lda + k0 + half * 32;
#pragma unroll
                for (int i = 0; i < 8; i++) fv[i] = ((const float4*)ap)[i];
            } else {
#pragma unroll
                for (int i = 0; i < 8; i++) fv[i] = make_float4(0.f, 0.f, 0.f, 0.f);
            }
#pragma unroll
            for (int ci = 0; ci < 4; ci++) {
                uint4 q;
                q.x = pk2(fv[2*ci].x,   fv[2*ci].y);
                q.y = pk2(fv[2*ci].z,   fv[2*ci].w);
                q.z = pk2(fv[2*ci+1].x, fv[2*ci+1].y);
                q.w = pk2(fv[2*ci+1].z, fv[2*ci+1].w);
                int slot = half * 4 + ci;
                int phys = slot ^ (r & 7);
                *(uint4*)&lsA[r * GBK + phys * 8] = q;
            }
        }
        // ---- stage B: straight bf16 copy, same swizzle ----
        {
            const unsigned short* bp = brow + k0 + half * 32;
#pragma unroll
            for (int ci = 0; ci < 4; ci++) {
                uint4 q = ((const uint4*)bp)[ci];
                int slot = half * 4 + ci;
                int phys = slot ^ (r & 7);
                *(uint4*)&lsB[r * GBK + phys * 8] = q;
            }
        }
        __syncthreads();
        // ---- 2 k-steps of 16x16x32 MFMAs ----
#pragma unroll
        for (int ks = 0; ks < 2; ks++) {
            bf16x8 bfr[4];
#pragma unroll
            for (int n = 0; n < 4; n++) {
                int rn = wn * 64 + n * 16 + (l & 15);
                int phys = (ks * 4 + (l >> 4)) ^ (rn & 7);
                bfr[n] = *(bf16x8*)&lsB[rn * GBK + phys * 8];
            }
#pragma unroll
            for (int m = 0; m < 4; m++) {
                int rm = wm * 64 + m * 16 + (l & 15);
                int phys = (ks * 4 + (l >> 4)) ^ (rm & 7);
                bf16x8 af = *(bf16x8*)&lsA[rm * GBK + phys * 8];
#pragma unroll
                for (int n = 0; n < 4; n++)
                    acc[m][n] = __builtin_amdgcn_mfma_f32_16x16x32_bf16(af, bfr[n], acc[m][n], 0, 0, 0);
            }
        }
        __syncthreads();
    }

    // ---- epilogue: acc row = (lane>>4)*4 + i, col = lane&15 ----
    if constexpr (BF16OUT) {
        // stage to LDS ([128][128] bf16, 16B-chunk XOR swizzle), then stream out 16B stores
        unsigned short* Cb = (unsigned short*)Cout;
#pragma unroll
        for (int n = 0; n < 4; n++) {
            int cl = wn * 64 + n * 16 + (l & 15);
            float bv = bias ? bias[col0 + cl] : 0.0f;
#pragma unroll
            for (int m = 0; m < 4; m++) {
                int rbase = wm * 64 + m * 16 + (l >> 4) * 4;
#pragma unroll
                for (int i = 0; i < 4; i++) {
                    int rl = rbase + i;
                    float o = acc[m][n][i] + bv;
                    if (EPI == 1) o = silu_f(o);
                    int chunk = cl >> 3;
                    int phys = chunk ^ (rl & 15);
                    smem[rl * 128 + phys * 8 + (cl & 7)] = f2bf(o);
                }
            }
        }
        __syncthreads();
        int orow = tid >> 1, hf = tid & 1;
        int rr = row0 + orow;
        if (rr < M) {
            unsigned short* crow = Cb + (size_t)rr * Nc + col0;
#pragma unroll
            for (int c8 = 0; c8 < 8; c8++) {
                int chunk = hf * 8 + c8;
                int phys = chunk ^ (orow & 15);
                uint4 v = *(uint4*)&smem[orow * 128 + phys * 8];
                *(uint4*)(crow + chunk * 8) = v;
            }
        }
    } else {
        float* Cf = (float*)Cout;
        const int cbase = col0 + wn * 64 + (l & 15);
#pragma unroll
        for (int n = 0; n < 4; n++) {
            int c = cbase + n * 16;
            float bv = bias ? bias[c] : 0.0f;
#pragma unroll
            for (int m = 0; m < 4; m++) {
                int rbase = row0 + wm * 64 + m * 16 + (l >> 4) * 4;
#pragma unroll
                for (int i = 0; i < 4; i++) {
                    int rr = rbase + i;
                    if (rr >= M) continue;
                    float o = acc[m][n][i];
                    if (EPI == 2) {
                        float cf = (float)cnt[rr];
                        o = (o + cf * bv) / fmaxf(cf, 1.0f);
                    } else {
                        o += bv;
                        if (EPI == 1) o = silu_f(o);
                    }
                    size_t off = (size_t)rr * Nc + c;
                    if (EPI == 3) Cf[off] += o;
                    else          Cf[off] = o;
                }
            }
        }
    }
}

// ---------------- fused msg + CSR aggregation (bf16 in, fp32 accum, bf16 u, NO atomics) ----------------
// Pab[node][512]: cols 0-255 = Pa (src term), cols 256-511 = Pb (dst term)
// FIRST chunk: every node WRITES u (zeros if no edges -> u fully initialized, no memset).
// Later chunks: RMW, early-exit when no edges in range. Chunks stream-serialized -> race-free.
template <bool FIRST>
__global__ void agg_kernel(const unsigned short* __restrict__ Pab,
                           const unsigned short* __restrict__ Pe, const int* __restrict__ esrc,
                           const int* __restrict__ rowptr,
                           unsigned short* __restrict__ u, int e0, int e1)
{
    int node = blockIdx.x * 4 + (threadIdx.x >> 6);
    if (node >= NN) return;
    int beg = rowptr[node], end = rowptr[node + 1];
    int lo = beg > e0 ? beg : e0;
    int hi = end < e1 ? end : e1;
    if (!FIRST && lo >= hi) return;
    int lane = threadIdx.x & 63;
    int j = lane * 4;
    float a0 = 0.f, a1 = 0.f, a2 = 0.f, a3 = 0.f;
    if (lo < hi) {
        ushort4 pb4 = *(const ushort4*)(Pab + (size_t)node * 512 + 256 + j);
        float b0 = bf2f(pb4.x), b1 = bf2f(pb4.y), b2 = bf2f(pb4.z), b3 = bf2f(pb4.w);
        int p = lo;
        int src = esrc[p];
        ushort4 pa = *(const ushort4*)(Pab + (size_t)src * 512 + j);
        ushort4 pe = *(const ushort4*)(Pe + (size_t)(p - e0) * HH + j);
        for (;;) {
            ushort4 cpa = pa, cpe = pe;
            int np = p + 1;
            if (np < hi) {
                int s2 = esrc[np];
                pa = *(const ushort4*)(Pab + (size_t)s2 * 512 + j);
                pe = *(const ushort4*)(Pe + (size_t)(np - e0) * HH + j);
            }
            a0 += silu_f(bf2f(cpa.x) + b0 + bf2f(cpe.x));
            a1 += silu_f(bf2f(cpa.y) + b1 + bf2f(cpe.y));
            a2 += silu_f(bf2f(cpa.z) + b2 + bf2f(cpe.z));
            a3 += silu_f(bf2f(cpa.w) + b3 + bf2f(cpe.w));
            if (np >= hi) break;
            p = np;
        }
    }
    unsigned short* up = u + (size_t)node * HH + j;
    if (!FIRST) {
        ushort4 uo = *(const ushort4*)up;
        a0 += bf2f(uo.x); a1 += bf2f(uo.y); a2 += bf2f(uo.z); a3 += bf2f(uo.w);
    }
    ushort4 o;
    o.x = f2bf(a0); o.y = f2bf(a1); o.z = f2bf(a2); o.w = f2bf(a3);
    *(ushort4*)up = o;
}

// ---------------- edge_index normalization (int64-vs-int32 autodetect) ----------------
// Benign-race plain store (all writers store 0) -- NOT atomic: same-address atomics
// serialized ~5000 waves and cost 59 us/launch.
__global__ void detect_kernel(const uint32_t* __restrict__ w, int* flag)
{
    int i = blockIdx.x * 256 + threadIdx.x;
    bool bad = false;
    if (i < NE) {  // only scan first half -> reads stay in-bounds for either layout
        uint32_t lo = w[2 * i], hi = w[2 * i + 1];
        bad = (hi != 0u) || (lo >= (uint32_t)NN);
    }
    if (__any(bad)) {
        if ((threadIdx.x & 63) == 0) *flag = 0;
    }
}
__global__ void convert_kernel(const uint32_t* __restrict__ w, const int* __restrict__ flag,
                               int* __restrict__ out)
{
    int i = blockIdx.x * 256 + threadIdx.x;
    if (i >= 2 * NE) return;
    out[i] = (*flag) ? (int)w[2 * i] : (int)w[i];
}
__global__ void deg_kernel(const int* __restrict__ idx, int* __restrict__ cnt)
{
    int e = blockIdx.x * 256 + threadIdx.x;
    if (e < NE) atomicAdd(cnt + idx[NE + e], 1);
}

// ---------------- exclusive prefix scan of cnt[NN] -> rowptr[NN+1], single block ----------------
__global__ void scan_kernel(const int* __restrict__ cnt, int* __restrict__ rowptr)
{
    __shared__ int part[1024];
    const int T = 1024, PER = (NN + T - 1) / T;
    int t = threadIdx.x;
    int base = t * PER;
    int s = 0;
    for (int i = 0; i < PER; i++) {
        int idx = base + i;
        if (idx < NN) s += cnt[idx];
    }
    part[t] = s;
    __syncthreads();
    for (int off = 1; off < T; off <<= 1) {
        int v = (t >= off) ? part[t - off] : 0;
        __syncthreads();
        part[t] += v;
        __syncthreads();
    }
    int run = (t == 0) ? 0 : part[t - 1];
    for (int i = 0; i < PER; i++) {
        int idx = base + i;
        if (idx < NN) { rowptr[idx] = run; run += cnt[idx]; }
    }
    if (t == T - 1) rowptr[NN] = part[T - 1];
}

// ---------------- scatter edges into dst-sorted order ----------------
__global__ void fill_kernel(const int* __restrict__ idx, const int* __restrict__ rowptr,
                            int* __restrict__ fillc, int* __restrict__ esrc,
                            int* __restrict__ eorig)
{
    int e = blockIdx.x * 256 + threadIdx.x;
    if (e >= NE) return;
    int dst = idx[NE + e];
    int pos = rowptr[dst] + atomicAdd(fillc + dst, 1);
    esrc[pos]  = idx[e];
    eorig[pos] = e;
}

// ---------------- launcher ----------------
extern "C" void kernel_launch(void* const* d_in, const int* in_sizes, int n_in,
                              void* d_out, int out_size, void* d_ws, size_t ws_size,
                              hipStream_t stream)
{
    const float* node_state = (const float*)d_in[0];
    const float* edge_attr  = (const float*)d_in[1];
    const float* nn_g = (const float*)d_in[2];
    const float* nn_b = (const float*)d_in[3];
    const float* mn_g = (const float*)d_in[4];
    const float* mn_b = (const float*)d_in[5];
    const float* eW1  = (const float*)d_in[6];
    const float* eb1  = (const float*)d_in[7];
    const float* eW2  = (const float*)d_in[8];
    const float* eb2  = (const float*)d_in[9];
    const float* nW1  = (const float*)d_in[10];
    const float* nb1  = (const float*)d_in[11];
    const float* nW2  = (const float*)d_in[12];
    const float* nb2  = (const float*)d_in[13];
    const uint32_t* eidx_raw = (const uint32_t*)d_in[14];

    const size_t SZ = (size_t)NN * HH;                  // 5,120,000
    unsigned short* hn  = (unsigned short*)d_ws;        // NN*HH bf16 (10.24 MB)
    unsigned short* u   = hn + SZ;                      // NN*HH bf16 (10.24 MB)
    unsigned short* Pab = u + SZ;                       // NN*512 bf16 (20.48 MB)
    unsigned short* eas = Pab + (size_t)NN * 512;       // NE*EDK bf16 (40.96 MB)
    unsigned short* Pe  = eas + (size_t)NE * EDK;       // ECH*HH bf16 (81.92 MB)
    //   aliases inside the Pe region (all used only after chunks complete):
    float* aggp = (float*)Pe;                                                   // NN*HH fp32 (20.48 MB)
    unsigned short* aggb = (unsigned short*)((char*)Pe + 22000000);             // NN*HH bf16 (10.24 MB)
    unsigned short* zb   = (unsigned short*)((char*)Pe + 34000000);             // NN*512 bf16 (20.48 MB)
    unsigned short* wbuf = Pe + (size_t)ECH * HH;       // 4*WSTEP bf16 (4.85 MB)
    int* idx32  = (int*)(wbuf + 4 * WSTEP);
    int* esrc   = idx32 + 2 * NE;
    int* eorig  = esrc + NE;
    int* rowptr = eorig + NE;      // NN+1
    int* cnt    = rowptr + NN + 1;
    int* fillc  = cnt + NN;
    int* flag   = fillc + NN;
    size_t needed = ((size_t)(flag + 1) - (size_t)d_ws);
    if (ws_size < needed) return;  // insufficient scratch: fail verification, don't crash

    float* h = (float*)d_out;

    hipMemcpyAsync(h, node_state, SZ * sizeof(float), hipMemcpyDeviceToDevice, stream);

    // ---- preprocessing ----
    wtr_kernel<<<4 * 592, 256, 0, stream>>>(eW1, eW2, nW1, nW2, wbuf);
    hipMemsetAsync(flag, 0xFF, sizeof(int), stream);
    detect_kernel<<<(NE + 255) / 256, 256, 0, stream>>>(eidx_raw, flag);
    convert_kernel<<<(2 * NE + 255) / 256, 256, 0, stream>>>(eidx_raw, flag, idx32);
    hipMemsetAsync(cnt, 0, NN * sizeof(int), stream);
    deg_kernel<<<(NE + 255) / 256, 256, 0, stream>>>(idx32, cnt);
    scan_kernel<<<1, 1024, 0, stream>>>(cnt, rowptr);
    hipMemsetAsync(fillc, 0, NN * sizeof(int), stream);
    fill_kernel<<<(NE + 255) / 256, 256, 0, stream>>>(idx32, rowptr, fillc, esrc, eorig);
    easort_kernel<<<(NE * 16) / 256, 256, 0, stream>>>(edge_attr, eorig, eas);

    const dim3 gN2((NN + GBM - 1) / GBM, 2);   // Nc=256
    const dim3 gN4((NN + GBM - 1) / GBM, 4);   // Nc=512
    const dim3 gPe(ECH / GBM, 2);

    for (int s = 0; s < NSTEPS; s++) {
        const unsigned short* wb = wbuf + (size_t)s * WSTEP;
        const unsigned short* WabT = wb;            // [512][256]: Wa^T rows 0-255, Wb^T rows 256-511
        const unsigned short* WcT  = wb + 131072;   // [256][64]
        const unsigned short* eW2T = wb + 147456;   // [256][256]
        const unsigned short* nW1T = wb + 212992;   // [512][512]
        const unsigned short* nW2T = wb + 475136;   // [256][512]
        const float* eb1s = eb1 + (size_t)s * HH;
        const float* eb2s = eb2 + (size_t)s * HH;
        const float* nb1s = nb1 + (size_t)s * 512;
        const float* nb2s = nb2 + (size_t)s * HH;

        // hn = bf16(LN(h))
        ln_kernel<<<NN / 4, 256, 0, stream>>>(h, nn_g + s * HH, nn_b + s * HH, hn, NN);
        // Pab = bf16(hn @ [Wa|Wb])  (one GEMM, Nc=512, bf16 A)
        mgemm<0, 3, true><<<gN4, 256, 0, stream>>>(hn, nullptr, HH, WabT, nullptr, nullptr, Pab, NN, 512, HH);
        // u = segment_sum over sorted edges of silu(Pa[src]+Pb[dst]+ea_sorted@Wc+eb1)
        {
            // chunk 0 (writes u, including zero rows)
            mgemm<0, 3, true><<<gPe, 256, 0, stream>>>(eas, nullptr, EDK, WcT, eb1s, nullptr, Pe, ECH, HH, EDK);
            agg_kernel<true><<<(NN + 3) / 4, 256, 0, stream>>>(Pab, Pe, esrc, rowptr, u, 0, ECH);
            // chunk 1 (RMW)
            mgemm<0, 3, true><<<gPe, 256, 0, stream>>>(eas + (size_t)ECH * EDK, nullptr, EDK, WcT, eb1s, nullptr, Pe, ECH, HH, EDK);
            agg_kernel<false><<<(NN + 3) / 4, 256, 0, stream>>>(Pab, Pe, esrc, rowptr, u, ECH, NE);
        }
        // aggp = (u @ eW2 + cnt*eb2)/max(cnt,1)  [fp32] ; aggb = bf16(LN(aggp))
        mgemm<2, 3, false><<<gN2, 256, 0, stream>>>(u, nullptr, HH, eW2T, eb2s, cnt, aggp, NN, HH, HH);
        ln_kernel<<<NN / 4, 256, 0, stream>>>(aggp, mn_g + s * HH, mn_b + s * HH, aggb, NN);
        // zb = bf16(silu([hn, aggb] @ nW1 + nb1))
        mgemm<1, 4, true><<<gN4, 256, 0, stream>>>(hn, aggb, HH, nW1T, nb1s, nullptr, zb, NN, 512, 512);
        // h += zb @ nW2 + nb2
        mgemm<3, 3, false><<<gN2, 256, 0, stream>>>(zb, nullptr, 512, nW2T, nb2s, nullptr, h, NN, HH, 512);
    }
}